// Round 5
// baseline (788.906 us; speedup 1.0000x reference)
//
#include <hip/hip_runtime.h>

typedef __attribute__((ext_vector_type(8))) short short8;
typedef __attribute__((ext_vector_type(4))) float f32x4;
typedef unsigned short ushort_t;
typedef unsigned int uint_t;

// ---------------- workspace layout (float offsets) ----------------
#define OFF_W1R   0
#define OFF_W2R   288
#define OFF_W3R   (288+18432)            // 18720
#define OFF_EWT   (18720+73728)          // 92448   (legacy, unused)
#define OFF_CT    (92448+147456)         // 239904  (legacy, unused)
#define OFF_CC    (239904+131072)        // 370976  cc[1024]
#define OFF_DWT   (370976+1024)          // 372000  dwt[k][1152j]
#define OFF_D1R   (372000+147456)        // 519456
#define OFF_D2R   (519456+73728)         // 593184
#define OFF_D3R   (593184+18432)         // 611616
#define WS_WEIGHTS (611616+288)          // 611904
#define OFF_W2BF  WS_WEIGHTS             // bf16 hi/lo conv2 w: [plane][tap][co64][ch32]
#define OFF_W3BF  (OFF_W2BF+18432)       // bf16 hi/lo conv3 w: [plane][tap][co128][ch64]
#define OFF_H     (OFF_W3BF+73728)       // h [8192][1152] fp32 (dead after fc_argmin)
#define OFF_TABLE OFF_H                  // decoded table [1024][576] overlays dead h
#define OFF_IDSN  (OFF_H+8192*1152)      // ids [8192] int

__device__ __forceinline__ ushort_t f2bf(float v) {
  uint_t u = __float_as_uint(v);
  return (ushort_t)((u + 0x7FFFu + ((u >> 16) & 1u)) >> 16);
}
__device__ __forceinline__ float bf2f(ushort_t b) {
  return __uint_as_float(((uint_t)b) << 16);
}

__global__ void vq_prep(const float* __restrict__ conv1_w, const float* __restrict__ codebook,
                        const float* __restrict__ dec_fc_w,
                        const float* __restrict__ dct1_w, const float* __restrict__ dct2_w,
                        const float* __restrict__ dct3_w, float* __restrict__ ws) {
  int i = blockIdx.x * blockDim.x + threadIdx.x;
  if (i >= WS_WEIGHTS) return;
  if (i < OFF_W2R) {
    int tap = i >> 5, co = i & 31;
    ws[i] = conv1_w[co*9 + tap];
  } else if (i < OFF_CC) {
    return;  // legacy regions unused
  } else if (i < OFF_DWT) {
    int k = i - OFF_CC;
    float s = 0.f;
    for (int j = 0; j < 128; ++j) { float v = codebook[k*128+j]; s += v*v; }
    ws[i] = s;
  } else if (i < OFF_D1R) {
    int l = i - OFF_DWT;
    int j = l % 1152, k = l / 1152;
    ws[i] = dec_fc_w[j*128 + k];
  } else if (i < OFF_D2R) {
    int l = i - OFF_D1R;
    int co = l & 63, r = l >> 6, tap = r % 9, ci = r / 9;
    ws[i] = dct1_w[(ci*64 + co)*9 + (8 - tap)];
  } else if (i < OFF_D3R) {
    int l = i - OFF_D2R;
    int co = l & 31, r = l >> 5, tap = r % 9, ci = r / 9;
    ws[i] = dct2_w[(ci*32 + co)*9 + (8 - tap)];
  } else {
    int l = i - OFF_D3R;
    int tap = l % 9, ci = l / 9;
    ws[i] = dct3_w[ci*9 + (8 - tap)];
  }
}

// bf16 hi/lo weight planes for MFMA convs
__global__ void vq_prep2(const float* __restrict__ conv2_w, const float* __restrict__ conv3_w,
                         float* __restrict__ ws) {
  int i = blockIdx.x * blockDim.x + threadIdx.x;
  ushort_t* W2 = (ushort_t*)(ws + OFF_W2BF);
  ushort_t* W3 = (ushort_t*)(ws + OFF_W3BF);
  if (i < 18432) {
    int tap = i >> 11, r = i & 2047, co = r >> 5, ch = r & 31;
    float v = conv2_w[(co*32 + ch)*9 + tap];
    ushort_t hb = f2bf(v);
    W2[i] = hb; W2[18432 + i] = f2bf(v - bf2f(hb));
  } else if (i < 92160) {
    int j = i - 18432;
    int tap = j >> 13, r = j & 8191, co = r >> 6, ch = r & 63;
    float v = conv3_w[(co*64 + ch)*9 + tap];
    ushort_t hb = f2bf(v);
    W3[j] = hb; W3[73728 + j] = f2bf(v - bf2f(hb));
  }
}

// ---------------- encoder: 1 sample/block, conv2/conv3 via MFMA bf16x3 ----------------
// R0: conv1-out [4 chgrp][14x14 pixels][8 ch] x2 planes (bank-uniform 2-way reads)
// A2: conv2-out [8 chgrp][8 rows x 10 colstride][8 ch] x2 planes
__global__ __launch_bounds__(256, 3) void vq_enc(
    const float* __restrict__ x,
    const float* __restrict__ b1, const float* __restrict__ b2, const float* __restrict__ b3,
    const float* __restrict__ ws, float* __restrict__ hout)
{
  __shared__ ushort_t R0h[6272], R0l[6272];
  __shared__ ushort_t A2h[5120], A2l[5120];
  __shared__ float XT[624];
  const int t = threadIdx.x;
  const int b = blockIdx.x;

  for (int i = t; i < 3136; i += 256) { ((uint_t*)R0h)[i] = 0u; ((uint_t*)R0l)[i] = 0u; }
  for (int i = t; i < 2560; i += 256) { ((uint_t*)A2h)[i] = 0u; ((uint_t*)A2l)[i] = 0u; }
  const float* xb = x + (size_t)b * 576;
  for (int i = t; i < 624; i += 256) {
    int row = i / 26, c = i - row * 26;
    XT[i] = (c >= 1 && c <= 24) ? xb[row*24 + c - 1] : 0.f;
  }
  __syncthreads();

  // ---- conv1 (1->32) + relu + pool (vector fp32), packed u32 stores ----
  {
    int cp = t & 15, g = t >> 4;          // cp: channel pair (2cp, 2cp+1)
    int gy = g >> 2, gx = g & 3;          // gy wave-uniform (= wave id)
    float wgt[2][9], bs[2];
    #pragma unroll
    for (int c = 0; c < 2; ++c) {
      bs[c] = b1[2*cp + c];
      #pragma unroll
      for (int k = 0; k < 9; ++k) wgt[c][k] = ws[OFF_W1R + k*32 + 2*cp + c];
    }
    int quadc = cp >> 2, coff = (cp & 3) * 2;
    #pragma unroll
    for (int pr = 0; pr < 3; ++pr) {
      int Y = (gy*3 + pr)*2;
      float a0[2][6], a1[2][6];
      #pragma unroll
      for (int c = 0; c < 2; ++c)
        #pragma unroll
        for (int i = 0; i < 6; ++i) { a0[c][i] = 0.f; a1[c][i] = 0.f; }
      #pragma unroll
      for (int wy = 0; wy < 4; ++wy) {
        int ry = Y - 1 + wy;
        if (ry < 0 || ry > 23) continue;   // wave-uniform (gy uniform)
        const float2* rp = (const float2*)&XT[ry*26 + gx*6];
        float r[8];
        #pragma unroll
        for (int k = 0; k < 4; ++k) { float2 p = rp[k]; r[2*k] = p.x; r[2*k+1] = p.y; }
        if (wy < 3) {
          #pragma unroll
          for (int c = 0; c < 2; ++c)
            #pragma unroll
            for (int xx = 0; xx < 6; ++xx)
              #pragma unroll
              for (int dx = 0; dx < 3; ++dx) a0[c][xx] += r[xx+dx] * wgt[c][wy*3+dx];
        }
        if (wy >= 1) {
          #pragma unroll
          for (int c = 0; c < 2; ++c)
            #pragma unroll
            for (int xx = 0; xx < 6; ++xx)
              #pragma unroll
              for (int dx = 0; dx < 3; ++dx) a1[c][xx] += r[xx+dx] * wgt[c][(wy-1)*3+dx];
        }
      }
      #pragma unroll
      for (int pc = 0; pc < 3; ++pc) {
        uint_t hi = 0, lo = 0;
        #pragma unroll
        for (int c = 0; c < 2; ++c) {
          float m = fmaxf(fmaxf(a0[c][2*pc], a0[c][2*pc+1]), fmaxf(a1[c][2*pc], a1[c][2*pc+1]));
          float v = m + bs[c]; v = v > 0.f ? v : 0.f;
          ushort_t hb = f2bf(v);
          ushort_t lb = f2bf(v - bf2f(hb));
          hi |= ((uint_t)hb) << (16*c);
          lo |= ((uint_t)lb) << (16*c);
        }
        int p = (gy*3 + pr + 1)*14 + (gx*3 + pc + 1);
        int base = quadc*1568 + p*8 + coff;       // ushort idx, even
        ((uint_t*)R0h)[base >> 1] = hi;
        ((uint_t*)R0l)[base >> 1] = lo;
      }
    }
  }
  __syncthreads();

  const int lane = t & 63, wv = t >> 6;
  const int col = lane & 15, quad = lane >> 4;

  // ---- conv2 (32->64, K=288) MFMA, M=144 = 9 exact tiles, mt-major waves ----
  {
    const ushort_t* W2 = (const ushort_t*)(ws + OFF_W2BF);
    const int mtb = (wv == 0) ? 0 : (wv == 1) ? 3 : (wv == 2) ? 5 : 7;
    const int cnt = (wv == 0) ? 3 : 2;
    int pA[3];
    #pragma unroll
    for (int mi = 0; mi < 3; ++mi) {
      int mt = mtb + (mi < cnt ? mi : 0);
      int cell = mt*4 + (col >> 2), sub = col & 3;
      int y = 2*(cell/6) + (sub >> 1), xx = 2*(cell%6) + (sub & 1);
      pA[mi] = y*14 + xx;
    }
    f32x4 acc[3][4];
    #pragma unroll
    for (int mi = 0; mi < 3; ++mi)
      #pragma unroll
      for (int nt = 0; nt < 4; ++nt) acc[mi][nt] = (f32x4)0.f;
    #pragma unroll
    for (int t9 = 0; t9 < 9; ++t9) {
      const int toff = (t9/3)*14 + (t9%3);
      short8 Bh[4], Bl[4];
      #pragma unroll
      for (int nt = 0; nt < 4; ++nt) {
        int co = nt*16 + col;
        Bh[nt] = *(const short8*)(W2 + t9*2048 + co*32 + quad*8);
        Bl[nt] = *(const short8*)(W2 + 18432 + t9*2048 + co*32 + quad*8);
      }
      #pragma unroll
      for (int mi = 0; mi < 3; ++mi) {
        if (mi < cnt) {
          int a = quad*1568 + (pA[mi] + toff)*8;
          short8 Ah = *(const short8*)(R0h + a);
          short8 Al = *(const short8*)(R0l + a);
          #pragma unroll
          for (int nt = 0; nt < 4; ++nt) {
            acc[mi][nt] = __builtin_amdgcn_mfma_f32_16x16x32_bf16(Al, Bh[nt], acc[mi][nt], 0,0,0);
            acc[mi][nt] = __builtin_amdgcn_mfma_f32_16x16x32_bf16(Ah, Bl[nt], acc[mi][nt], 0,0,0);
            acc[mi][nt] = __builtin_amdgcn_mfma_f32_16x16x32_bf16(Ah, Bh[nt], acc[mi][nt], 0,0,0);
          }
        }
      }
    }
    // epilogue: in-register 2x2 pool + bias + relu -> A2 planes
    #pragma unroll
    for (int mi = 0; mi < 3; ++mi) {
      if (mi < cnt) {
        int mt = mtb + mi;
        int cell = mt*4 + quad;                    // 0..35, all valid
        int p2 = ((cell/6) + 1)*10 + (cell%6) + 1;
        #pragma unroll
        for (int nt = 0; nt < 4; ++nt) {
          int ch = nt*16 + col;
          f32x4 a = acc[mi][nt];
          float v = fmaxf(fmaxf(a.x, a.y), fmaxf(a.z, a.w)) + b2[ch];
          v = v > 0.f ? v : 0.f;
          ushort_t hb = f2bf(v);
          int wa = (ch >> 3)*640 + p2*8 + (ch & 7);
          A2h[wa] = hb;
          A2l[wa] = f2bf(v - bf2f(hb));
        }
      }
    }
  }
  __syncthreads();

  // ---- conv3 (64->128, K=576) MFMA, M=36 (3 tiles), nt-pair-major waves ----
  {
    const ushort_t* W3 = (const ushort_t*)(ws + OFF_W3BF);
    int pA[3];
    #pragma unroll
    for (int mt = 0; mt < 3; ++mt) {
      int cell = mt*4 + (col >> 2);
      if (cell > 8) cell = 8;                      // pad rows read valid junk
      int sub = col & 3;
      int y = 2*(cell/3) + (sub >> 1), xx = 2*(cell%3) + (sub & 1);
      pA[mt] = y*10 + xx;
    }
    f32x4 acc[3][2];
    #pragma unroll
    for (int mt = 0; mt < 3; ++mt) { acc[mt][0] = (f32x4)0.f; acc[mt][1] = (f32x4)0.f; }
    #pragma unroll
    for (int ks = 0; ks < 18; ++ks) {
      const int t9 = ks >> 1, half = ks & 1;
      const int toff = (t9/3)*10 + (t9%3);
      const int grp = half*4 + quad;
      short8 Bh[2], Bl[2];
      #pragma unroll
      for (int j = 0; j < 2; ++j) {
        int co = (wv*2 + j)*16 + col;
        int bo = t9*8192 + co*64 + half*32 + quad*8;
        Bh[j] = *(const short8*)(W3 + bo);
        Bl[j] = *(const short8*)(W3 + 73728 + bo);
      }
      #pragma unroll
      for (int mt = 0; mt < 3; ++mt) {
        int a = grp*640 + (pA[mt] + toff)*8;
        short8 Ah = *(const short8*)(A2h + a);
        short8 Al = *(const short8*)(A2l + a);
        #pragma unroll
        for (int j = 0; j < 2; ++j) {
          acc[mt][j] = __builtin_amdgcn_mfma_f32_16x16x32_bf16(Al, Bh[j], acc[mt][j], 0,0,0);
          acc[mt][j] = __builtin_amdgcn_mfma_f32_16x16x32_bf16(Ah, Bl[j], acc[mt][j], 0,0,0);
          acc[mt][j] = __builtin_amdgcn_mfma_f32_16x16x32_bf16(Ah, Bh[j], acc[mt][j], 0,0,0);
        }
      }
    }
    float* hb_ = hout + (size_t)b * 1152;
    #pragma unroll
    for (int mt = 0; mt < 3; ++mt) {
      int cell = mt*4 + quad;
      if (cell < 9) {
        #pragma unroll
        for (int j = 0; j < 2; ++j) {
          int ch = (wv*2 + j)*16 + col;
          f32x4 a = acc[mt][j];
          float v = fmaxf(fmaxf(a.x, a.y), fmaxf(a.z, a.w)) + b3[ch];
          v = v > 0.f ? v : 0.f;
          hb_[ch*9 + cell] = v;
        }
      }
    }
  }
}

// ---------------- fused enc_fc + argmin: 16 samples/block (fp32 vector) ----------------
__global__ __launch_bounds__(256, 2) void vq_fc_argmin(
    const float* __restrict__ efw, const float* __restrict__ efb,
    const float* __restrict__ cb, const float* __restrict__ ws,
    const float* __restrict__ h, int* __restrict__ ids)
{
  __shared__ float HT[18432];
  __shared__ float WVs[64];
  __shared__ int   WIs[64];
  const int t = threadIdx.x;
  const int sb = blockIdx.x * 16;

  const float4* src = (const float4*)(h + (size_t)sb * 1152);
  for (int i = t; i < 4608; i += 256) ((float4*)HT)[i] = src[i];
  __syncthreads();

  const int j = t & 127, g = t >> 7;
  float acc[8];
  #pragma unroll
  for (int u = 0; u < 8; ++u) acc[u] = 0.f;
  const float* wj = efw + (size_t)j * 1152;
  for (int k4 = 0; k4 < 1152; k4 += 4) {
    float4 wvv = *(const float4*)(wj + k4);
    const float* hp = &HT[g*9216 + k4];
    #pragma unroll
    for (int u = 0; u < 8; ++u) {
      float4 hv = *(const float4*)(hp + u*1152);
      acc[u] += wvv.x*hv.x + wvv.y*hv.y + wvv.z*hv.z + wvv.w*hv.w;
    }
  }
  float bias = efb[j];
  __syncthreads();
  #pragma unroll
  for (int u = 0; u < 8; ++u) HT[(g*8 + u)*128 + j] = acc[u] + bias;
  __syncthreads();

  float bestv[16]; int besti[16];
  #pragma unroll
  for (int s = 0; s < 16; ++s) { bestv[s] = 3.4e38f; besti[s] = 0; }
  for (int c = 0; c < 4; ++c) {
    int cw = c*256 + t;
    float d[16];
    #pragma unroll
    for (int s = 0; s < 16; ++s) d[s] = 0.f;
    const float* cp = cb + (size_t)cw * 128;
    for (int k4 = 0; k4 < 128; k4 += 4) {
      float4 cv = *(const float4*)(cp + k4);
      #pragma unroll
      for (int s = 0; s < 16; ++s) {
        float4 zv = *(const float4*)(&HT[s*128 + k4]);
        d[s] += cv.x*zv.x + cv.y*zv.y + cv.z*zv.z + cv.w*zv.w;
      }
    }
    float ccv = ws[OFF_CC + cw];
    #pragma unroll
    for (int s = 0; s < 16; ++s) {
      float dist = ccv - 2.f*d[s];
      if (dist < bestv[s]) { bestv[s] = dist; besti[s] = cw; }
    }
  }
  const int lane = t & 63, wid = t >> 6;
  #pragma unroll
  for (int s = 0; s < 16; ++s) {
    float v = bestv[s]; int ii = besti[s];
    #pragma unroll
    for (int off = 32; off >= 1; off >>= 1) {
      float v2 = __shfl_xor(v, off); int i2 = __shfl_xor(ii, off);
      if (v2 < v || (v2 == v && i2 < ii)) { v = v2; ii = i2; }
    }
    if (lane == 0) { WVs[wid*16 + s] = v; WIs[wid*16 + s] = ii; }
  }
  __syncthreads();
  if (t < 16) {
    float v = WVs[t]; int ii = WIs[t];
    #pragma unroll
    for (int w2 = 1; w2 < 4; ++w2) {
      float v2 = WVs[w2*16 + t]; int i2 = WIs[w2*16 + t];
      if (v2 < v || (v2 == v && i2 < ii)) { v = v2; ii = i2; }
    }
    ids[sb + t] = ii;
  }
}

// ---------------- decode table: 1 codeword per block, 1024 blocks ----------------
__global__ __launch_bounds__(256, 4) void vq_dec_table(
    const float* __restrict__ codebook, const float* __restrict__ decb,
    const float* __restrict__ d1b, const float* __restrict__ d2b, const float* __restrict__ d3b,
    const float* __restrict__ ws, float* __restrict__ table)
{
  __shared__ float DB[1152];
  __shared__ float R1[2432];
  __shared__ float R0[4736];
  __shared__ float ZQ[128];
  const int t = threadIdx.x;
  const int cw = blockIdx.x;

  if (t < 128) ZQ[t] = codebook[(size_t)cw*128 + t];
  __syncthreads();

  // ---- dec_fc (128->1152) ----
  #pragma unroll
  for (int p = 0; p < 5; ++p) {
    int j = t + p*256;
    if (j < 1152) {
      float a0 = decb[j];
      const float* wb = ws + OFF_DWT + j;
      #pragma unroll 4
      for (int k = 0; k < 128; ++k) a0 += wb[k*1152] * ZQ[k];
      DB[j] = a0;
    }
  }
  __syncthreads();

  // ---- D1 (128->64) + relu + upsample -> R1 [64@38] ----
  {
    int co = t & 63, g = t >> 6;
    float a9[9];
    #pragma unroll
    for (int i = 0; i < 9; ++i) a9[i] = 0.f;
    const float* wbase = ws + OFF_D1R + co;
    for (int ci = g*32; ci < g*32+32; ++ci) {
      float w[9];
      #pragma unroll
      for (int k = 0; k < 9; ++k) w[k] = wbase[(ci*9+k)*64];
      const float* fin = DB + ci*9;
      #pragma unroll
      for (int ry = 0; ry < 3; ++ry) {
        float r[5];
        r[0] = 0.f; r[4] = 0.f;
        r[1] = fin[ry*3]; r[2] = fin[ry*3+1]; r[3] = fin[ry*3+2];
        #pragma unroll
        for (int y = 0; y < 3; ++y) {
          int d = ry - y + 1;
          if (d >= 0 && d < 3) {
            #pragma unroll
            for (int xx = 0; xx < 3; ++xx)
              #pragma unroll
              for (int dx = 0; dx < 3; ++dx) a9[y*3+xx] += r[xx+dx] * w[d*3+dx];
          }
        }
      }
    }
    __syncthreads();
    if (g) {
      #pragma unroll
      for (int i = 0; i < 9; ++i) R0[((g-1)*64 + co)*9 + i] = a9[i];
    }
    __syncthreads();
    if (!g) {
      float bias = d1b[co];
      #pragma unroll
      for (int i = 0; i < 9; ++i)
        a9[i] += R0[co*9 + i] + R0[(64+co)*9 + i] + R0[(128+co)*9 + i];
      #pragma unroll
      for (int yy = 0; yy < 3; ++yy)
        #pragma unroll
        for (int xx = 0; xx < 3; ++xx) {
          float v = a9[yy*3+xx] + bias; v = v > 0.f ? v : 0.f;
          int base = co*38 + (2*yy)*6 + 2*xx;
          R1[base] = v; R1[base+1] = v; R1[base+6] = v; R1[base+7] = v;
        }
    }
  }
  __syncthreads();

  // ---- D2 (64->32) + relu + upsample -> R0 [32@146] ----
  {
    int co = t & 31, hh = (t >> 5) & 1, g = t >> 6;
    int sy = g >> 1, sx = g & 1;
    float a9[9];
    #pragma unroll
    for (int i = 0; i < 9; ++i) a9[i] = 0.f;
    const float* wbase = ws + OFF_D2R + co;
    for (int ci = hh*32; ci < hh*32+32; ++ci) {
      float w[9];
      #pragma unroll
      for (int k = 0; k < 9; ++k) w[k] = wbase[(ci*9+k)*32];
      const float* base = &R1[ci*38];
      #pragma unroll
      for (int wy = 0; wy < 5; ++wy) {
        int ry = sy*3 - 1 + wy;
        if (ry < 0 || ry > 5) continue;
        const float* row = base + ry*6 + sx*3;
        float r[5];
        if (sx == 0) {
          r[0] = 0.f; r[1] = row[0]; r[2] = row[1]; r[3] = row[2]; r[4] = row[3];
        } else {
          r[0] = row[-1]; r[1] = row[0]; r[2] = row[1]; r[3] = row[2]; r[4] = 0.f;
        }
        #pragma unroll
        for (int y = 0; y < 3; ++y) {
          int d = wy - 1 - y + 1;
          if (d >= 0 && d < 3) {
            #pragma unroll
            for (int xx = 0; xx < 3; ++xx)
              #pragma unroll
              for (int dx = 0; dx < 3; ++dx) a9[y*3+xx] += r[xx+dx] * w[d*3+dx];
          }
        }
      }
    }
    __syncthreads();
    if (hh) {
      #pragma unroll
      for (int i = 0; i < 9; ++i) DB[(g*32 + co)*9 + i] = a9[i];
    }
    __syncthreads();
    if (!hh) {
      float bias = d2b[co];
      #pragma unroll
      for (int i = 0; i < 9; ++i) a9[i] += DB[(g*32 + co)*9 + i];
      #pragma unroll
      for (int yy = 0; yy < 3; ++yy)
        #pragma unroll
        for (int xx = 0; xx < 3; ++xx) {
          float v = a9[yy*3+xx] + bias; v = v > 0.f ? v : 0.f;
          int rr = sy*3 + yy, cc_ = sx*3 + xx;
          int base = co*146 + (2*rr)*12 + 2*cc_;
          R0[base] = v; R0[base+1] = v; R0[base+12] = v; R0[base+13] = v;
        }
    }
  }
  __syncthreads();

  // ---- D3 (32->1) + relu + upsample -> table[cw] ----
  if (t < 144) {
    int yy = t / 12, xx = t - yy*12;
    const float* w3 = ws + OFF_D3R;
    float acc = d3b[0];
    for (int ci = 0; ci < 32; ++ci) {
      const float* base = &R0[ci*146];
      #pragma unroll
      for (int dy = 0; dy < 3; ++dy) {
        int ry = yy - 1 + dy;
        int ryc = ry < 0 ? 0 : (ry > 11 ? 11 : ry);
        bool rok = (ry >= 0 && ry < 12);
        #pragma unroll
        for (int dx = 0; dx < 3; ++dx) {
          int rx = xx - 1 + dx;
          int rxc = rx < 0 ? 0 : (rx > 11 ? 11 : rx);
          float v = base[ryc*12 + rxc];
          v = (rok && rx >= 0 && rx < 12) ? v : 0.f;
          acc += v * w3[ci*9 + dy*3 + dx];
        }
      }
    }
    float v = acc > 0.f ? acc : 0.f;
    float* ob = table + (size_t)cw * 576;
    int o0 = (2*yy)*24 + 2*xx;
    ob[o0] = v; ob[o0+1] = v; ob[o0+24] = v; ob[o0+25] = v;
  }
}

// ---------------- scatter: out[b] = table[ids[b]] ----------------
__global__ __launch_bounds__(256, 8) void vq_scatter(
    const float* __restrict__ table, const int* __restrict__ ids,
    float* __restrict__ out, int nvec)
{
  int idx = blockIdx.x * 256 + threadIdx.x;     // float4 index
  if (idx >= nvec) return;
  int b = idx / 144;
  int r = idx - b * 144;
  int cw = ids[b];
  ((float4*)out)[idx] = ((const float4*)(table + (size_t)cw * 576))[r];
}

extern "C" void kernel_launch(void* const* d_in, const int* in_sizes, int n_in,
                              void* d_out, int out_size, void* d_ws, size_t ws_size,
                              hipStream_t stream) {
  const float* x   = (const float*)d_in[0];
  const float* c1w = (const float*)d_in[1];
  const float* c1b = (const float*)d_in[2];
  const float* c2w = (const float*)d_in[3];
  const float* c2b = (const float*)d_in[4];
  const float* c3w = (const float*)d_in[5];
  const float* c3b = (const float*)d_in[6];
  const float* efw = (const float*)d_in[7];
  const float* efb = (const float*)d_in[8];
  const float* cb  = (const float*)d_in[9];
  const float* dfw = (const float*)d_in[10];
  const float* dfb = (const float*)d_in[11];
  const float* dw1 = (const float*)d_in[12];
  const float* db1 = (const float*)d_in[13];
  const float* dw2 = (const float*)d_in[14];
  const float* db2 = (const float*)d_in[15];
  const float* dw3 = (const float*)d_in[16];
  const float* db3 = (const float*)d_in[17];
  float* ws = (float*)d_ws;
  float* h     = ws + OFF_H;
  float* table = ws + OFF_TABLE;
  int*   ids   = (int*)(ws + OFF_IDSN);
  float* outp = (float*)d_out;
  int B = in_sizes[0] / 576;

  vq_prep<<<(WS_WEIGHTS + 255) / 256, 256, 0, stream>>>(c1w, cb, dfw, dw1, dw2, dw3, ws);
  vq_prep2<<<(92160 + 255) / 256, 256, 0, stream>>>(c2w, c3w, ws);
  vq_enc<<<B, 256, 0, stream>>>(x, c1b, c2b, c3b, ws, h);
  vq_fc_argmin<<<B/16, 256, 0, stream>>>(efw, efb, cb, ws, h, ids);
  vq_dec_table<<<1024, 256, 0, stream>>>(cb, dfb, db1, db2, db3, ws, table);
  int nvec = B * 144;
  vq_scatter<<<(nvec + 255) / 256, 256, 0, stream>>>(table, ids, outp, nvec);
}

// Round 6
// 634.145 us; speedup vs baseline: 1.2440x; 1.2440x over previous
//
#include <hip/hip_runtime.h>

typedef __attribute__((ext_vector_type(8))) short short8;
typedef __attribute__((ext_vector_type(4))) float f32x4;
typedef unsigned short ushort_t;
typedef unsigned int uint_t;

// ---------------- workspace layout (float offsets) ----------------
#define OFF_W1R   0
#define OFF_W2R   288
#define OFF_W3R   (288+18432)            // 18720
#define OFF_EWT   (18720+73728)          // 92448   efw bf16 frags [pl][36ks][128n][32k] (294912 us)
#define OFF_CT    (92448+147456)         // 239904  codebook bf16 frags [pl][4ks][1024n][32k] (262144 us)
#define OFF_CC    (239904+131072)        // 370976  cc[1024]
#define OFF_DWT   (370976+1024)          // 372000  dwt[k][1152j]
#define OFF_D1R   (372000+147456)        // 519456
#define OFF_D2R   (519456+73728)         // 593184
#define OFF_D3R   (593184+18432)         // 611616
#define WS_WEIGHTS (611616+288)          // 611904
#define OFF_W2BF  WS_WEIGHTS             // bf16 hi/lo conv2 w: [plane][tap][co64][ch32]
#define OFF_W3BF  (OFF_W2BF+18432)       // bf16 hi/lo conv3 w: [plane][tap][co128][ch64]
#define OFF_H     (OFF_W3BF+73728)       // h bf16 hi/lo planes [2][8192][1152] ushort
#define OFF_TABLE OFF_H                  // decoded table [1024][576] fp32 overlays dead h
#define OFF_IDSN  (OFF_H+8192*1152)      // ids [8192] int

__device__ __forceinline__ ushort_t f2bf(float v) {
  uint_t u = __float_as_uint(v);
  return (ushort_t)((u + 0x7FFFu + ((u >> 16) & 1u)) >> 16);
}
__device__ __forceinline__ float bf2f(ushort_t b) {
  return __uint_as_float(((uint_t)b) << 16);
}

__global__ void vq_prep(const float* __restrict__ conv1_w, const float* __restrict__ codebook,
                        const float* __restrict__ dec_fc_w,
                        const float* __restrict__ dct1_w, const float* __restrict__ dct2_w,
                        const float* __restrict__ dct3_w, float* __restrict__ ws) {
  int i = blockIdx.x * blockDim.x + threadIdx.x;
  if (i >= WS_WEIGHTS) return;
  if (i < OFF_W2R) {
    int tap = i >> 5, co = i & 31;
    ws[i] = conv1_w[co*9 + tap];
  } else if (i < OFF_CC) {
    return;  // EWT/CT regions written by vq_prep2
  } else if (i < OFF_DWT) {
    int k = i - OFF_CC;
    float s = 0.f;
    for (int j = 0; j < 128; ++j) { float v = codebook[k*128+j]; s += v*v; }
    ws[i] = s;
  } else if (i < OFF_D1R) {
    int l = i - OFF_DWT;
    int j = l % 1152, k = l / 1152;
    ws[i] = dec_fc_w[j*128 + k];
  } else if (i < OFF_D2R) {
    int l = i - OFF_D1R;
    int co = l & 63, r = l >> 6, tap = r % 9, ci = r / 9;
    ws[i] = dct1_w[(ci*64 + co)*9 + (8 - tap)];
  } else if (i < OFF_D3R) {
    int l = i - OFF_D2R;
    int co = l & 31, r = l >> 5, tap = r % 9, ci = r / 9;
    ws[i] = dct2_w[(ci*32 + co)*9 + (8 - tap)];
  } else {
    int l = i - OFF_D3R;
    int tap = l % 9, ci = l / 9;
    ws[i] = dct3_w[ci*9 + (8 - tap)];
  }
}

// bf16 hi/lo weight planes: conv2, conv3, enc_fc (B-frag layout), codebook (B-frag layout)
#define P2_N (92160 + 294912 + 262144)
__global__ void vq_prep2(const float* __restrict__ conv2_w, const float* __restrict__ conv3_w,
                         const float* __restrict__ enc_fc_w, const float* __restrict__ codebook,
                         float* __restrict__ ws) {
  int i = blockIdx.x * blockDim.x + threadIdx.x;
  if (i >= P2_N) return;
  ushort_t* W2 = (ushort_t*)(ws + OFF_W2BF);
  ushort_t* W3 = (ushort_t*)(ws + OFF_W3BF);
  ushort_t* EW = (ushort_t*)(ws + OFF_EWT);
  ushort_t* CB = (ushort_t*)(ws + OFF_CT);
  if (i < 18432) {
    int tap = i >> 11, r = i & 2047, co = r >> 5, ch = r & 31;
    float v = conv2_w[(co*32 + ch)*9 + tap];
    ushort_t hb = f2bf(v);
    W2[i] = hb; W2[18432 + i] = f2bf(v - bf2f(hb));
  } else if (i < 92160) {
    int j = i - 18432;
    int tap = j >> 13, r = j & 8191, co = r >> 6, ch = r & 63;
    float v = conv3_w[(co*64 + ch)*9 + tap];
    ushort_t hb = f2bf(v);
    W3[j] = hb; W3[73728 + j] = f2bf(v - bf2f(hb));
  } else if (i < 92160 + 294912) {
    int e = i - 92160;
    int p = e / 147456, r = e % 147456;
    int kk = r & 31, n = (r >> 5) & 127, ks = r >> 12;
    float v = enc_fc_w[n*1152 + ks*32 + kk];
    ushort_t hb = f2bf(v);
    EW[r] = (p == 0) ? EW[r] : EW[r];   // placeholder avoided below
    if (p == 0) EW[r] = hb; else EW[147456 + r] = f2bf(v - bf2f(hb));
  } else {
    int e = i - 92160 - 294912;
    int p = e / 131072, r = e % 131072;
    int kk = r & 31, cw = (r >> 5) & 1023, ks = r >> 15;
    float v = codebook[cw*128 + ks*32 + kk];
    ushort_t hb = f2bf(v);
    if (p == 0) CB[r] = hb; else CB[131072 + r] = f2bf(v - bf2f(hb));
  }
}

// ---------------- encoder: 1 sample/block, conv2/conv3 via MFMA bf16x3 (round-4 structure) ----
__global__ __launch_bounds__(256, 3) void vq_enc(
    const float* __restrict__ x,
    const float* __restrict__ b1, const float* __restrict__ b2, const float* __restrict__ b3,
    const float* __restrict__ ws, ushort_t* __restrict__ hhi, ushort_t* __restrict__ hlo)
{
  __shared__ ushort_t R0h[7840], R0l[7840];   // conv1-out [14][14][40]
  __shared__ ushort_t C3h[4608], C3l[4608];   // conv2-out [8][8][72]
  __shared__ float XT[624];                    // x [24][26] col-padded
  const int t = threadIdx.x;
  const int b = blockIdx.x;

  for (int i = t; i < 3920; i += 256) { ((uint_t*)R0h)[i] = 0u; ((uint_t*)R0l)[i] = 0u; }
  for (int i = t; i < 2304; i += 256) { ((uint_t*)C3h)[i] = 0u; ((uint_t*)C3l)[i] = 0u; }
  const float* xb = x + (size_t)b * 576;
  for (int i = t; i < 624; i += 256) {
    int row = i / 26, col = i - row * 26;
    XT[i] = (col >= 1 && col <= 24) ? xb[row*24 + col - 1] : 0.f;
  }
  __syncthreads();

  // ---- conv1 (1->32) + relu + pool (vector fp32) ----
  {
    int co = t & 31, g = t >> 5, gy = g >> 1, gx = g & 1;
    float w[9];
    #pragma unroll
    for (int k = 0; k < 9; ++k) w[k] = ws[OFF_W1R + k*32 + co];
    float bias = b1[co];
    #pragma unroll
    for (int pr = 0; pr < 3; ++pr) {
      int Y = gy*6 + pr*2;
      float a0[12], a1[12];
      #pragma unroll
      for (int i = 0; i < 12; ++i) { a0[i] = 0.f; a1[i] = 0.f; }
      #pragma unroll
      for (int wy = 0; wy < 4; ++wy) {
        int ry = Y - 1 + wy;
        if (ry < 0 || ry > 23) continue;
        const float2* rp = (const float2*)&XT[ry*26 + gx*12];
        float r[14];
        #pragma unroll
        for (int k = 0; k < 7; ++k) { float2 p = rp[k]; r[2*k] = p.x; r[2*k+1] = p.y; }
        if (wy < 3) {
          #pragma unroll
          for (int xx = 0; xx < 12; ++xx)
            #pragma unroll
            for (int dx = 0; dx < 3; ++dx) a0[xx] += r[xx+dx] * w[wy*3+dx];
        }
        if (wy >= 1) {
          #pragma unroll
          for (int xx = 0; xx < 12; ++xx)
            #pragma unroll
            for (int dx = 0; dx < 3; ++dx) a1[xx] += r[xx+dx] * w[(wy-1)*3+dx];
        }
      }
      #pragma unroll
      for (int pc = 0; pc < 6; ++pc) {
        float m = fmaxf(fmaxf(a0[2*pc], a0[2*pc+1]), fmaxf(a1[2*pc], a1[2*pc+1]));
        float v = m + bias; v = v > 0.f ? v : 0.f;
        int row = gy*3 + pr, colp = gx*6 + pc;
        int addr = ((row+1)*14 + (colp+1))*40 + co;
        ushort_t hb = f2bf(v);
        R0h[addr] = hb;
        R0l[addr] = f2bf(v - bf2f(hb));
      }
    }
  }
  __syncthreads();

  const int lane = t & 63, quad = lane >> 4, col = lane & 15;
  const int wv = t >> 6;

  // ---- conv2 (32->64, K=288) MFMA, M=144 pool-grouped (+pad to 160) ----
  {
    const int h = wv & 1, p = wv >> 1;
    const ushort_t* W2 = (const ushort_t*)(ws + OFF_W2BF);
    int baseA[5];
    #pragma unroll
    for (int mi = 0; mi < 5; ++mi) {
      int m = (h*5 + mi)*16 + col; if (m > 143) m = 143;
      int cell = m >> 2, sub = m & 3;
      int opy = cell / 6, opx = cell - opy*6;
      int y = 2*opy + (sub >> 1), xx = 2*opx + (sub & 1);
      baseA[mi] = (y*14 + xx)*40 + quad*8;
    }
    f32x4 acc[5][2];
    #pragma unroll
    for (int mi = 0; mi < 5; ++mi) { acc[mi][0] = (f32x4)0.f; acc[mi][1] = (f32x4)0.f; }
    const int co0 = p*32 + col, co1 = co0 + 16;
    #pragma unroll
    for (int t9 = 0; t9 < 9; ++t9) {
      const int TAPOFF = ((t9/3)*14 + (t9%3))*40;
      int bidx = t9*2048 + quad*8;
      short8 Bh0 = *(const short8*)(W2 + bidx + co0*32);
      short8 Bh1 = *(const short8*)(W2 + bidx + co1*32);
      short8 Bl0 = *(const short8*)(W2 + 18432 + bidx + co0*32);
      short8 Bl1 = *(const short8*)(W2 + 18432 + bidx + co1*32);
      #pragma unroll
      for (int mi = 0; mi < 5; ++mi) {
        int a = baseA[mi] + TAPOFF;
        short8 Ah = *(const short8*)(R0h + a);
        short8 Al = *(const short8*)(R0l + a);
        acc[mi][0] = __builtin_amdgcn_mfma_f32_16x16x32_bf16(Al, Bh0, acc[mi][0], 0, 0, 0);
        acc[mi][0] = __builtin_amdgcn_mfma_f32_16x16x32_bf16(Ah, Bl0, acc[mi][0], 0, 0, 0);
        acc[mi][0] = __builtin_amdgcn_mfma_f32_16x16x32_bf16(Ah, Bh0, acc[mi][0], 0, 0, 0);
        acc[mi][1] = __builtin_amdgcn_mfma_f32_16x16x32_bf16(Al, Bh1, acc[mi][1], 0, 0, 0);
        acc[mi][1] = __builtin_amdgcn_mfma_f32_16x16x32_bf16(Ah, Bl1, acc[mi][1], 0, 0, 0);
        acc[mi][1] = __builtin_amdgcn_mfma_f32_16x16x32_bf16(Ah, Bh1, acc[mi][1], 0, 0, 0);
      }
    }
    #pragma unroll
    for (int mi = 0; mi < 5; ++mi) {
      int cell = (h*5 + mi)*4 + quad;
      if (cell < 36) {
        int opy = cell / 6, opx = cell - opy*6;
        int wa = ((opy+1)*8 + (opx+1))*72;
        #pragma unroll
        for (int j = 0; j < 2; ++j) {
          int ch = j ? co1 : co0;
          f32x4 a = acc[mi][j];
          float v = fmaxf(fmaxf(a.x, a.y), fmaxf(a.z, a.w)) + b2[ch];
          v = v > 0.f ? v : 0.f;
          ushort_t hb = f2bf(v);
          C3h[wa + ch] = hb;
          C3l[wa + ch] = f2bf(v - bf2f(hb));
        }
      }
    }
  }
  __syncthreads();

  // ---- conv3 (64->128, K=576) MFMA ----
  {
    const ushort_t* W3 = (const ushort_t*)(ws + OFF_W3BF);
    int baseA[3];
    #pragma unroll
    for (int mt = 0; mt < 3; ++mt) {
      int m = mt*16 + col; if (m > 35) m = 35;
      int cell = m >> 2, sub = m & 3;
      int opy = cell / 3, opx = cell - opy*3;
      int y = 2*opy + (sub >> 1), xx = 2*opx + (sub & 1);
      baseA[mt] = (y*8 + xx)*72 + quad*8;
    }
    f32x4 acc[3][2];
    #pragma unroll
    for (int mt = 0; mt < 3; ++mt) { acc[mt][0] = (f32x4)0.f; acc[mt][1] = (f32x4)0.f; }
    const int co0 = wv*16 + col, co1 = co0 + 64;
    #pragma unroll
    for (int ks = 0; ks < 18; ++ks) {
      const int t9 = ks >> 1, ch0 = (ks & 1)*32;
      const int TAPOFF = ((t9/3)*8 + (t9%3))*72;
      int bidx = t9*8192 + ch0 + quad*8;
      short8 Bh0 = *(const short8*)(W3 + bidx + co0*64);
      short8 Bh1 = *(const short8*)(W3 + bidx + co1*64);
      short8 Bl0 = *(const short8*)(W3 + 73728 + bidx + co0*64);
      short8 Bl1 = *(const short8*)(W3 + 73728 + bidx + co1*64);
      #pragma unroll
      for (int mt = 0; mt < 3; ++mt) {
        int a = baseA[mt] + TAPOFF + ch0;
        short8 Ah = *(const short8*)(C3h + a);
        short8 Al = *(const short8*)(C3l + a);
        acc[mt][0] = __builtin_amdgcn_mfma_f32_16x16x32_bf16(Al, Bh0, acc[mt][0], 0, 0, 0);
        acc[mt][0] = __builtin_amdgcn_mfma_f32_16x16x32_bf16(Ah, Bl0, acc[mt][0], 0, 0, 0);
        acc[mt][0] = __builtin_amdgcn_mfma_f32_16x16x32_bf16(Ah, Bh0, acc[mt][0], 0, 0, 0);
        acc[mt][1] = __builtin_amdgcn_mfma_f32_16x16x32_bf16(Al, Bh1, acc[mt][1], 0, 0, 0);
        acc[mt][1] = __builtin_amdgcn_mfma_f32_16x16x32_bf16(Ah, Bl1, acc[mt][1], 0, 0, 0);
        acc[mt][1] = __builtin_amdgcn_mfma_f32_16x16x32_bf16(Ah, Bh1, acc[mt][1], 0, 0, 0);
      }
    }
    ushort_t* hb_ = hhi + (size_t)b * 1152;
    ushort_t* lb_ = hlo + (size_t)b * 1152;
    #pragma unroll
    for (int mt = 0; mt < 3; ++mt) {
      int cell = mt*4 + quad;
      if (cell < 9) {
        #pragma unroll
        for (int j = 0; j < 2; ++j) {
          int ch = j ? co1 : co0;
          f32x4 a = acc[mt][j];
          float v = fmaxf(fmaxf(a.x, a.y), fmaxf(a.z, a.w)) + b3[ch];
          v = v > 0.f ? v : 0.f;
          ushort_t hb2 = f2bf(v);
          hb_[ch*9 + cell] = hb2;
          lb_[ch*9 + cell] = f2bf(v - bf2f(hb2));
        }
      }
    }
  }
}

// ---------------- fused enc_fc + argmin via MFMA bf16x3: 16 samples/block ----------------
__global__ __launch_bounds__(256, 4) void vq_fc_argmin(
    const float* __restrict__ efb, const float* __restrict__ ws,
    const ushort_t* __restrict__ hhi, const ushort_t* __restrict__ hlo,
    int* __restrict__ ids)
{
  __shared__ float ZL[16*132];        // z [16 samples][128 ch] stride-132 (2-way banks)
  __shared__ float WVs[64];
  __shared__ int   WIs[64];
  const int t = threadIdx.x;
  const int sb = blockIdx.x * 16;
  const int lane = t & 63, wv = t >> 6;
  const int col = lane & 15, quad = lane >> 4;

  const ushort_t* EW  = (const ushort_t*)(ws + OFF_EWT);
  const ushort_t* CBB = (const ushort_t*)(ws + OFF_CT);

  // ---- enc_fc: z = h @ efw^T + b (M=16, K=1152, N=128; 2 n-tiles/wave) ----
  f32x4 acc0 = (f32x4)0.f, acc1 = (f32x4)0.f;
  const size_t hrow = (size_t)(sb + col) * 1152 + quad*8;
  #pragma unroll 4
  for (int ks = 0; ks < 36; ++ks) {
    short8 Ah = *(const short8*)(hhi + hrow + ks*32);
    short8 Al = *(const short8*)(hlo + hrow + ks*32);
    int n0 = wv*32 + col, n1 = n0 + 16;
    const ushort_t* bp0 = EW + (ks*128 + n0)*32 + quad*8;
    const ushort_t* bp1 = EW + (ks*128 + n1)*32 + quad*8;
    short8 Bh0 = *(const short8*)(bp0);
    short8 Bl0 = *(const short8*)(bp0 + 147456);
    short8 Bh1 = *(const short8*)(bp1);
    short8 Bl1 = *(const short8*)(bp1 + 147456);
    acc0 = __builtin_amdgcn_mfma_f32_16x16x32_bf16(Al, Bh0, acc0, 0, 0, 0);
    acc0 = __builtin_amdgcn_mfma_f32_16x16x32_bf16(Ah, Bl0, acc0, 0, 0, 0);
    acc0 = __builtin_amdgcn_mfma_f32_16x16x32_bf16(Ah, Bh0, acc0, 0, 0, 0);
    acc1 = __builtin_amdgcn_mfma_f32_16x16x32_bf16(Al, Bh1, acc1, 0, 0, 0);
    acc1 = __builtin_amdgcn_mfma_f32_16x16x32_bf16(Ah, Bl1, acc1, 0, 0, 0);
    acc1 = __builtin_amdgcn_mfma_f32_16x16x32_bf16(Ah, Bh1, acc1, 0, 0, 0);
  }
  {
    int n0 = wv*32 + col, n1 = n0 + 16;
    float bs0 = efb[n0], bs1 = efb[n1];
    #pragma unroll
    for (int r = 0; r < 4; ++r) {
      int m = quad*4 + r;
      ZL[m*132 + n0] = acc0[r] + bs0;
      ZL[m*132 + n1] = acc1[r] + bs1;
    }
  }
  __syncthreads();

  // ---- build z A-frags (hi/lo) in registers ----
  short8 zAh[4], zAl[4];
  #pragma unroll
  for (int ks = 0; ks < 4; ++ks) {
    const float* zp = &ZL[col*132 + ks*32 + quad*8];
    float4 z0 = *(const float4*)zp;
    float4 z1 = *(const float4*)(zp + 4);
    float zv[8] = {z0.x, z0.y, z0.z, z0.w, z1.x, z1.y, z1.z, z1.w};
    ushort_t ph[8], pl[8];
    #pragma unroll
    for (int e = 0; e < 8; ++e) {
      ushort_t hb = f2bf(zv[e]);
      ph[e] = hb; pl[e] = f2bf(zv[e] - bf2f(hb));
    }
    zAh[ks] = *(const short8*)ph;
    zAl[ks] = *(const short8*)pl;
  }

  // ---- distances: D = Z @ C^T (M=16, K=128, N=1024; 16 n-tiles/wave) ----
  float bestv[4]; int besti[4];
  #pragma unroll
  for (int r = 0; r < 4; ++r) { bestv[r] = 3.4e38f; besti[r] = 0; }
  for (int c4 = 0; c4 < 4; ++c4) {
    f32x4 dacc[4];
    #pragma unroll
    for (int nn = 0; nn < 4; ++nn) dacc[nn] = (f32x4)0.f;
    #pragma unroll
    for (int ks = 0; ks < 4; ++ks) {
      #pragma unroll
      for (int nn = 0; nn < 4; ++nn) {
        int cw = (wv*16 + c4*4 + nn)*16 + col;
        const ushort_t* bp = CBB + (size_t)(ks*1024 + cw)*32 + quad*8;
        short8 Bh = *(const short8*)bp;
        short8 Bl = *(const short8*)(bp + 131072);
        dacc[nn] = __builtin_amdgcn_mfma_f32_16x16x32_bf16(zAl[ks], Bh, dacc[nn], 0, 0, 0);
        dacc[nn] = __builtin_amdgcn_mfma_f32_16x16x32_bf16(zAh[ks], Bl, dacc[nn], 0, 0, 0);
        dacc[nn] = __builtin_amdgcn_mfma_f32_16x16x32_bf16(zAh[ks], Bh, dacc[nn], 0, 0, 0);
      }
    }
    #pragma unroll
    for (int nn = 0; nn < 4; ++nn) {
      int cw = (wv*16 + c4*4 + nn)*16 + col;
      float ccv = ws[OFF_CC + cw];
      #pragma unroll
      for (int r = 0; r < 4; ++r) {
        float dist = ccv - 2.f*dacc[nn][r];
        if (dist < bestv[r]) { bestv[r] = dist; besti[r] = cw; }
      }
    }
  }

  // ---- reduce across the 16 cols of each quad (stay within quad: off<=8) ----
  #pragma unroll
  for (int r = 0; r < 4; ++r) {
    float v = bestv[r]; int ii = besti[r];
    #pragma unroll
    for (int off = 8; off >= 1; off >>= 1) {
      float v2 = __shfl_xor(v, off); int i2 = __shfl_xor(ii, off);
      if (v2 < v || (v2 == v && i2 < ii)) { v = v2; ii = i2; }
    }
    if (col == 0) {
      int m = quad*4 + r;
      WVs[wv*16 + m] = v; WIs[wv*16 + m] = ii;
    }
  }
  __syncthreads();
  if (t < 16) {
    float v = WVs[t]; int ii = WIs[t];
    #pragma unroll
    for (int w2 = 1; w2 < 4; ++w2) {
      float v2 = WVs[w2*16 + t]; int i2 = WIs[w2*16 + t];
      if (v2 < v || (v2 == v && i2 < ii)) { v = v2; ii = i2; }
    }
    ids[sb + t] = ii;
  }
}

// ---------------- decode table: 1 codeword per block, 1024 blocks ----------------
__global__ __launch_bounds__(256, 4) void vq_dec_table(
    const float* __restrict__ codebook, const float* __restrict__ decb,
    const float* __restrict__ d1b, const float* __restrict__ d2b, const float* __restrict__ d3b,
    const float* __restrict__ ws, float* __restrict__ table)
{
  __shared__ float DB[1152];
  __shared__ float R1[2432];
  __shared__ float R0[4736];
  __shared__ float ZQ[128];
  const int t = threadIdx.x;
  const int cw = blockIdx.x;

  if (t < 128) ZQ[t] = codebook[(size_t)cw*128 + t];
  __syncthreads();

  #pragma unroll
  for (int p = 0; p < 5; ++p) {
    int j = t + p*256;
    if (j < 1152) {
      float a0 = decb[j];
      const float* wb = ws + OFF_DWT + j;
      #pragma unroll 4
      for (int k = 0; k < 128; ++k) a0 += wb[k*1152] * ZQ[k];
      DB[j] = a0;
    }
  }
  __syncthreads();

  {
    int co = t & 63, g = t >> 6;
    float a9[9];
    #pragma unroll
    for (int i = 0; i < 9; ++i) a9[i] = 0.f;
    const float* wbase = ws + OFF_D1R + co;
    for (int ci = g*32; ci < g*32+32; ++ci) {
      float w[9];
      #pragma unroll
      for (int k = 0; k < 9; ++k) w[k] = wbase[(ci*9+k)*64];
      const float* fin = DB + ci*9;
      #pragma unroll
      for (int ry = 0; ry < 3; ++ry) {
        float r[5];
        r[0] = 0.f; r[4] = 0.f;
        r[1] = fin[ry*3]; r[2] = fin[ry*3+1]; r[3] = fin[ry*3+2];
        #pragma unroll
        for (int y = 0; y < 3; ++y) {
          int d = ry - y + 1;
          if (d >= 0 && d < 3) {
            #pragma unroll
            for (int xx = 0; xx < 3; ++xx)
              #pragma unroll
              for (int dx = 0; dx < 3; ++dx) a9[y*3+xx] += r[xx+dx] * w[d*3+dx];
          }
        }
      }
    }
    __syncthreads();
    if (g) {
      #pragma unroll
      for (int i = 0; i < 9; ++i) R0[((g-1)*64 + co)*9 + i] = a9[i];
    }
    __syncthreads();
    if (!g) {
      float bias = d1b[co];
      #pragma unroll
      for (int i = 0; i < 9; ++i)
        a9[i] += R0[co*9 + i] + R0[(64+co)*9 + i] + R0[(128+co)*9 + i];
      #pragma unroll
      for (int yy = 0; yy < 3; ++yy)
        #pragma unroll
        for (int xx = 0; xx < 3; ++xx) {
          float v = a9[yy*3+xx] + bias; v = v > 0.f ? v : 0.f;
          int base = co*38 + (2*yy)*6 + 2*xx;
          R1[base] = v; R1[base+1] = v; R1[base+6] = v; R1[base+7] = v;
        }
    }
  }
  __syncthreads();

  {
    int co = t & 31, hh = (t >> 5) & 1, g = t >> 6;
    int sy = g >> 1, sx = g & 1;
    float a9[9];
    #pragma unroll
    for (int i = 0; i < 9; ++i) a9[i] = 0.f;
    const float* wbase = ws + OFF_D2R + co;
    for (int ci = hh*32; ci < hh*32+32; ++ci) {
      float w[9];
      #pragma unroll
      for (int k = 0; k < 9; ++k) w[k] = wbase[(ci*9+k)*32];
      const float* base = &R1[ci*38];
      #pragma unroll
      for (int wy = 0; wy < 5; ++wy) {
        int ry = sy*3 - 1 + wy;
        if (ry < 0 || ry > 5) continue;
        const float* row = base + ry*6 + sx*3;
        float r[5];
        if (sx == 0) {
          r[0] = 0.f; r[1] = row[0]; r[2] = row[1]; r[3] = row[2]; r[4] = row[3];
        } else {
          r[0] = row[-1]; r[1] = row[0]; r[2] = row[1]; r[3] = row[2]; r[4] = 0.f;
        }
        #pragma unroll
        for (int y = 0; y < 3; ++y) {
          int d = wy - 1 - y + 1;
          if (d >= 0 && d < 3) {
            #pragma unroll
            for (int xx = 0; xx < 3; ++xx)
              #pragma unroll
              for (int dx = 0; dx < 3; ++dx) a9[y*3+xx] += r[xx+dx] * w[d*3+dx];
          }
        }
      }
    }
    __syncthreads();
    if (hh) {
      #pragma unroll
      for (int i = 0; i < 9; ++i) DB[(g*32 + co)*9 + i] = a9[i];
    }
    __syncthreads();
    if (!hh) {
      float bias = d2b[co];
      #pragma unroll
      for (int i = 0; i < 9; ++i) a9[i] += DB[(g*32 + co)*9 + i];
      #pragma unroll
      for (int yy = 0; yy < 3; ++yy)
        #pragma unroll
        for (int xx = 0; xx < 3; ++xx) {
          float v = a9[yy*3+xx] + bias; v = v > 0.f ? v : 0.f;
          int rr = sy*3 + yy, cc_ = sx*3 + xx;
          int base = co*146 + (2*rr)*12 + 2*cc_;
          R0[base] = v; R0[base+1] = v; R0[base+12] = v; R0[base+13] = v;
        }
    }
  }
  __syncthreads();

  if (t < 144) {
    int yy = t / 12, xx = t - yy*12;
    const float* w3 = ws + OFF_D3R;
    float acc = d3b[0];
    for (int ci = 0; ci < 32; ++ci) {
      const float* base = &R0[ci*146];
      #pragma unroll
      for (int dy = 0; dy < 3; ++dy) {
        int ry = yy - 1 + dy;
        int ryc = ry < 0 ? 0 : (ry > 11 ? 11 : ry);
        bool rok = (ry >= 0 && ry < 12);
        #pragma unroll
        for (int dx = 0; dx < 3; ++dx) {
          int rx = xx - 1 + dx;
          int rxc = rx < 0 ? 0 : (rx > 11 ? 11 : rx);
          float v = base[ryc*12 + rxc];
          v = (rok && rx >= 0 && rx < 12) ? v : 0.f;
          acc += v * w3[ci*9 + dy*3 + dx];
        }
      }
    }
    float v = acc > 0.f ? acc : 0.f;
    float* ob = table + (size_t)cw * 576;
    int o0 = (2*yy)*24 + 2*xx;
    ob[o0] = v; ob[o0+1] = v; ob[o0+24] = v; ob[o0+25] = v;
  }
}

// ---------------- scatter: out[b] = table[ids[b]] ----------------
__global__ __launch_bounds__(256, 8) void vq_scatter(
    const float* __restrict__ table, const int* __restrict__ ids,
    float* __restrict__ out, int nvec)
{
  int idx = blockIdx.x * 256 + threadIdx.x;     // float4 index
  if (idx >= nvec) return;
  int b = idx / 144;
  int r = idx - b * 144;
  int cw = ids[b];
  ((float4*)out)[idx] = ((const float4*)(table + (size_t)cw * 576))[r];
}

extern "C" void kernel_launch(void* const* d_in, const int* in_sizes, int n_in,
                              void* d_out, int out_size, void* d_ws, size_t ws_size,
                              hipStream_t stream) {
  const float* x   = (const float*)d_in[0];
  const float* c1w = (const float*)d_in[1];
  const float* c1b = (const float*)d_in[2];
  const float* c2w = (const float*)d_in[3];
  const float* c2b = (const float*)d_in[4];
  const float* c3w = (const float*)d_in[5];
  const float* c3b = (const float*)d_in[6];
  const float* efw = (const float*)d_in[7];
  const float* efb = (const float*)d_in[8];
  const float* cb  = (const float*)d_in[9];
  const float* dfw = (const float*)d_in[10];
  const float* dfb = (const float*)d_in[11];
  const float* dw1 = (const float*)d_in[12];
  const float* db1 = (const float*)d_in[13];
  const float* dw2 = (const float*)d_in[14];
  const float* db2 = (const float*)d_in[15];
  const float* dw3 = (const float*)d_in[16];
  const float* db3 = (const float*)d_in[17];
  float* ws = (float*)d_ws;
  ushort_t* hhi  = (ushort_t*)(ws + OFF_H);
  ushort_t* hlo  = hhi + (size_t)8192*1152;
  float* table = ws + OFF_TABLE;     // overlays h (dead after fc_argmin)
  int*   ids   = (int*)(ws + OFF_IDSN);
  float* outp = (float*)d_out;
  int B = in_sizes[0] / 576;

  vq_prep<<<(WS_WEIGHTS + 255) / 256, 256, 0, stream>>>(c1w, cb, dfw, dw1, dw2, dw3, ws);
  vq_prep2<<<(P2_N + 255) / 256, 256, 0, stream>>>(c2w, c3w, efw, cb, ws);
  vq_enc<<<B, 256, 0, stream>>>(x, c1b, c2b, c3b, ws, hhi, hlo);
  vq_fc_argmin<<<B/16, 256, 0, stream>>>(efb, ws, hhi, hlo, ids);
  vq_dec_table<<<1024, 256, 0, stream>>>(cb, dfb, db1, db2, db3, ws, table);
  int nvec = B * 144;
  vq_scatter<<<(nvec + 255) / 256, 256, 0, stream>>>(table, ids, outp, nvec);
}

// Round 7
// 633.249 us; speedup vs baseline: 1.2458x; 1.0014x over previous
//
#include <hip/hip_runtime.h>

typedef __attribute__((ext_vector_type(8))) short short8;
typedef __attribute__((ext_vector_type(4))) float f32x4;
typedef unsigned short ushort_t;
typedef unsigned int uint_t;

// ---------------- workspace layout (float offsets) ----------------
#define OFF_W1R   0
#define OFF_BD2F  288                   // D2 convT bf16 B-frags hi/lo [co32][k=tap*64+ci] (36864 us)
#define OFF_BD1F  18720                 // D1 convT bf16 B-frags hi/lo [co64][k=tap*128+ci] (147456 us)
#define OFF_EWT   (18720+73728)         // 92448   efw bf16 frags hi/lo [36ks][128n][32k]
#define OFF_CT    (92448+147456)        // 239904  codebook bf16 frags hi/lo [4ks][1024n][32k]
#define OFF_CC    (239904+131072)       // 370976  cc[1024]
#define OFF_DWT   (370976+1024)         // 372000  dwt[k][1152j]
#define OFF_D1R   (372000+147456)       // 519456  (legacy fp32 dec weights, unused now)
#define OFF_D2R   (519456+73728)        // 593184
#define OFF_D3R   (593184+18432)        // 611616  dct3 flipped [ci*9+tap]
#define WS_WEIGHTS (611616+288)         // 611904
#define OFF_W2BF  WS_WEIGHTS            // bf16 hi/lo conv2 w: [plane][tap][co64][ch32]
#define OFF_W3BF  (OFF_W2BF+18432)      // bf16 hi/lo conv3 w: [plane][tap][co128][ch64]
#define OFF_H     (OFF_W3BF+73728)      // h bf16 hi/lo planes [2][8192][1152] ushort
#define OFF_TABLE OFF_H                 // decoded table [1024][576] fp32 overlays dead h
#define OFF_IDSN  (OFF_H+8192*1152)     // ids [8192] int

__device__ __forceinline__ ushort_t f2bf(float v) {
  uint_t u = __float_as_uint(v);
  return (ushort_t)((u + 0x7FFFu + ((u >> 16) & 1u)) >> 16);
}
__device__ __forceinline__ float bf2f(ushort_t b) {
  return __uint_as_float(((uint_t)b) << 16);
}

__global__ void vq_prep(const float* __restrict__ conv1_w, const float* __restrict__ codebook,
                        const float* __restrict__ dec_fc_w, const float* __restrict__ dct3_w,
                        float* __restrict__ ws) {
  int i = blockIdx.x * blockDim.x + threadIdx.x;
  if (i >= WS_WEIGHTS) return;
  if (i < OFF_BD2F) {
    int tap = i >> 5, co = i & 31;
    ws[i] = conv1_w[co*9 + tap];
  } else if (i < OFF_CC) {
    return;  // BD2/BD1/EWT/CT written by vq_prep2
  } else if (i < OFF_DWT) {
    int k = i - OFF_CC;
    float s = 0.f;
    for (int j = 0; j < 128; ++j) { float v = codebook[k*128+j]; s += v*v; }
    ws[i] = s;
  } else if (i < OFF_D1R) {
    int l = i - OFF_DWT;
    int j = l % 1152, k = l / 1152;
    ws[i] = dec_fc_w[j*128 + k];
  } else if (i < OFF_D3R) {
    return;  // legacy fp32 D1R/D2R regions unused
  } else if (i < WS_WEIGHTS) {
    int l = i - OFF_D3R;
    int tap = l % 9, ci = l / 9;
    ws[i] = dct3_w[ci*9 + (8 - tap)];
  }
}

// bf16 hi/lo frags: conv2, conv3, enc_fc, codebook, D1 convT, D2 convT
#define P2_N (92160 + 294912 + 262144 + 73728 + 18432)
__global__ void vq_prep2(const float* __restrict__ conv2_w, const float* __restrict__ conv3_w,
                         const float* __restrict__ enc_fc_w, const float* __restrict__ codebook,
                         const float* __restrict__ dct1_w, const float* __restrict__ dct2_w,
                         float* __restrict__ ws) {
  int i = blockIdx.x * blockDim.x + threadIdx.x;
  if (i >= P2_N) return;
  ushort_t* W2  = (ushort_t*)(ws + OFF_W2BF);
  ushort_t* W3  = (ushort_t*)(ws + OFF_W3BF);
  ushort_t* EW  = (ushort_t*)(ws + OFF_EWT);
  ushort_t* CB  = (ushort_t*)(ws + OFF_CT);
  ushort_t* BD1 = (ushort_t*)(ws + OFF_BD1F);
  ushort_t* BD2 = (ushort_t*)(ws + OFF_BD2F);
  if (i < 18432) {
    int tap = i >> 11, r = i & 2047, co = r >> 5, ch = r & 31;
    float v = conv2_w[(co*32 + ch)*9 + tap];
    ushort_t hb = f2bf(v);
    W2[i] = hb; W2[18432 + i] = f2bf(v - bf2f(hb));
  } else if (i < 92160) {
    int j = i - 18432;
    int tap = j >> 13, r = j & 8191, co = r >> 6, ch = r & 63;
    float v = conv3_w[(co*64 + ch)*9 + tap];
    ushort_t hb = f2bf(v);
    W3[j] = hb; W3[73728 + j] = f2bf(v - bf2f(hb));
  } else if (i < 387072) {
    int r = i - 92160;              // [0, 294912): p | [36ks][128n][32k]
    int p = r / 147456; r %= 147456;
    int kk = r & 31, n = (r >> 5) & 127, ks = r >> 12;
    float v = enc_fc_w[n*1152 + ks*32 + kk];
    ushort_t hb = f2bf(v);
    if (p == 0) EW[r] = hb; else EW[147456 + r] = f2bf(v - bf2f(hb));
  } else if (i < 649216) {
    int r = i - 387072;             // [0, 262144): p | [4ks][1024n][32k]
    int p = r / 131072; r %= 131072;
    int kk = r & 31, cw = (r >> 5) & 1023, ks = r >> 15;
    float v = codebook[cw*128 + ks*32 + kk];
    ushort_t hb = f2bf(v);
    if (p == 0) CB[r] = hb; else CB[131072 + r] = f2bf(v - bf2f(hb));
  } else if (i < 722944) {
    int r = i - 649216;             // BD1: [co64][k = tap*128 + ci]
    int co = r / 1152, k = r - co*1152;
    int tap = k >> 7, ci = k & 127;
    float v = dct1_w[(ci*64 + co)*9 + (8 - tap)];
    ushort_t hb = f2bf(v);
    BD1[r] = hb; BD1[73728 + r] = f2bf(v - bf2f(hb));
  } else {
    int r = i - 722944;             // BD2: [co32][k = tap*64 + ci]
    int co = r / 576, k = r - co*576;
    int tap = k >> 6, ci = k & 63;
    float v = dct2_w[(ci*32 + co)*9 + (8 - tap)];
    ushort_t hb = f2bf(v);
    BD2[r] = hb; BD2[18432 + r] = f2bf(v - bf2f(hb));
  }
}

// ---------------- encoder: 1 sample/block; round-6 wave mapping + round-5 compact layouts ----
// R0: [4 chgrp][14x14 ring pix][8 ch] hi/lo.  A2: [8 chgrp][8x10 ring pix][8 ch] hi/lo.
__global__ __launch_bounds__(256, 3) void vq_enc(
    const float* __restrict__ x,
    const float* __restrict__ b1, const float* __restrict__ b2, const float* __restrict__ b3,
    const float* __restrict__ ws, ushort_t* __restrict__ hhi, ushort_t* __restrict__ hlo)
{
  __shared__ ushort_t R0h[6272], R0l[6272];
  __shared__ ushort_t A2h[5120], A2l[5120];
  __shared__ float XT[624];
  const int t = threadIdx.x;
  const int b = blockIdx.x;

  for (int i = t; i < 3136; i += 256) { ((uint_t*)R0h)[i] = 0u; ((uint_t*)R0l)[i] = 0u; }
  for (int i = t; i < 2560; i += 256) { ((uint_t*)A2h)[i] = 0u; ((uint_t*)A2l)[i] = 0u; }
  const float* xb = x + (size_t)b * 576;
  for (int i = t; i < 624; i += 256) {
    int row = i / 26, c = i - row * 26;
    XT[i] = (c >= 1 && c <= 24) ? xb[row*24 + c - 1] : 0.f;
  }
  __syncthreads();

  // ---- conv1 (1->32) + relu + pool (vector fp32), packed u32 stores (round-5, verified) ----
  {
    int cp = t & 15, g = t >> 4;
    int gy = g >> 2, gx = g & 3;          // gy wave-uniform
    float wgt[2][9], bs[2];
    #pragma unroll
    for (int c = 0; c < 2; ++c) {
      bs[c] = b1[2*cp + c];
      #pragma unroll
      for (int k = 0; k < 9; ++k) wgt[c][k] = ws[OFF_W1R + k*32 + 2*cp + c];
    }
    int quadc = cp >> 2, coff = (cp & 3) * 2;
    #pragma unroll
    for (int pr = 0; pr < 3; ++pr) {
      int Y = (gy*3 + pr)*2;
      float a0[2][6], a1[2][6];
      #pragma unroll
      for (int c = 0; c < 2; ++c)
        #pragma unroll
        for (int i = 0; i < 6; ++i) { a0[c][i] = 0.f; a1[c][i] = 0.f; }
      #pragma unroll
      for (int wy = 0; wy < 4; ++wy) {
        int ry = Y - 1 + wy;
        if (ry < 0 || ry > 23) continue;   // wave-uniform
        const float2* rp = (const float2*)&XT[ry*26 + gx*6];
        float r[8];
        #pragma unroll
        for (int k = 0; k < 4; ++k) { float2 p = rp[k]; r[2*k] = p.x; r[2*k+1] = p.y; }
        if (wy < 3) {
          #pragma unroll
          for (int c = 0; c < 2; ++c)
            #pragma unroll
            for (int xx = 0; xx < 6; ++xx)
              #pragma unroll
              for (int dx = 0; dx < 3; ++dx) a0[c][xx] += r[xx+dx] * wgt[c][wy*3+dx];
        }
        if (wy >= 1) {
          #pragma unroll
          for (int c = 0; c < 2; ++c)
            #pragma unroll
            for (int xx = 0; xx < 6; ++xx)
              #pragma unroll
              for (int dx = 0; dx < 3; ++dx) a1[c][xx] += r[xx+dx] * wgt[c][(wy-1)*3+dx];
        }
      }
      #pragma unroll
      for (int pc = 0; pc < 3; ++pc) {
        uint_t hi = 0, lo = 0;
        #pragma unroll
        for (int c = 0; c < 2; ++c) {
          float m = fmaxf(fmaxf(a0[c][2*pc], a0[c][2*pc+1]), fmaxf(a1[c][2*pc], a1[c][2*pc+1]));
          float v = m + bs[c]; v = v > 0.f ? v : 0.f;
          ushort_t hb = f2bf(v);
          ushort_t lb = f2bf(v - bf2f(hb));
          hi |= ((uint_t)hb) << (16*c);
          lo |= ((uint_t)lb) << (16*c);
        }
        int p = (gy*3 + pr + 1)*14 + (gx*3 + pc + 1);
        int base = quadc*1568 + p*8 + coff;
        ((uint_t*)R0h)[base >> 1] = hi;
        ((uint_t*)R0l)[base >> 1] = lo;
      }
    }
  }
  __syncthreads();

  const int lane = t & 63, quad = lane >> 4, col = lane & 15;
  const int wv = t >> 6;

  // ---- conv2 (32->64, K=288) MFMA: balanced (m-half x n-pair), compact R0 addresses ----
  {
    const int h = wv & 1, p = wv >> 1;
    const ushort_t* W2 = (const ushort_t*)(ws + OFF_W2BF);
    int pA[5];
    #pragma unroll
    for (int mi = 0; mi < 5; ++mi) {
      int m = (h*5 + mi)*16 + col; if (m > 143) m = 143;
      int cell = m >> 2, sub = m & 3;
      int opy = cell / 6, opx = cell - opy*6;
      int y = 2*opy + (sub >> 1), xx = 2*opx + (sub & 1);
      pA[mi] = y*14 + xx;
    }
    f32x4 acc[5][2];
    #pragma unroll
    for (int mi = 0; mi < 5; ++mi) { acc[mi][0] = (f32x4)0.f; acc[mi][1] = (f32x4)0.f; }
    const int co0 = p*32 + col, co1 = co0 + 16;
    #pragma unroll
    for (int t9 = 0; t9 < 9; ++t9) {
      const int toff = (t9/3)*14 + (t9%3);
      int bidx = t9*2048 + quad*8;
      short8 Bh0 = *(const short8*)(W2 + bidx + co0*32);
      short8 Bh1 = *(const short8*)(W2 + bidx + co1*32);
      short8 Bl0 = *(const short8*)(W2 + 18432 + bidx + co0*32);
      short8 Bl1 = *(const short8*)(W2 + 18432 + bidx + co1*32);
      #pragma unroll
      for (int mi = 0; mi < 5; ++mi) {
        int a = quad*1568 + (pA[mi] + toff)*8;
        short8 Ah = *(const short8*)(R0h + a);
        short8 Al = *(const short8*)(R0l + a);
        acc[mi][0] = __builtin_amdgcn_mfma_f32_16x16x32_bf16(Al, Bh0, acc[mi][0], 0, 0, 0);
        acc[mi][0] = __builtin_amdgcn_mfma_f32_16x16x32_bf16(Ah, Bl0, acc[mi][0], 0, 0, 0);
        acc[mi][0] = __builtin_amdgcn_mfma_f32_16x16x32_bf16(Ah, Bh0, acc[mi][0], 0, 0, 0);
        acc[mi][1] = __builtin_amdgcn_mfma_f32_16x16x32_bf16(Al, Bh1, acc[mi][1], 0, 0, 0);
        acc[mi][1] = __builtin_amdgcn_mfma_f32_16x16x32_bf16(Ah, Bl1, acc[mi][1], 0, 0, 0);
        acc[mi][1] = __builtin_amdgcn_mfma_f32_16x16x32_bf16(Ah, Bh1, acc[mi][1], 0, 0, 0);
      }
    }
    #pragma unroll
    for (int mi = 0; mi < 5; ++mi) {
      int cell = (h*5 + mi)*4 + quad;
      if (cell < 36) {
        int opy = cell / 6, opx = cell - opy*6;
        int p2 = (opy+1)*10 + (opx+1);
        #pragma unroll
        for (int j = 0; j < 2; ++j) {
          int ch = j ? co1 : co0;
          f32x4 a = acc[mi][j];
          float v = fmaxf(fmaxf(a.x, a.y), fmaxf(a.z, a.w)) + b2[ch];
          v = v > 0.f ? v : 0.f;
          ushort_t hb = f2bf(v);
          int wa = (ch >> 3)*640 + p2*8 + (ch & 7);
          A2h[wa] = hb;
          A2l[wa] = f2bf(v - bf2f(hb));
        }
      }
    }
  }
  __syncthreads();

  // ---- conv3 (64->128, K=576) MFMA: n-pair waves, compact A2 addresses ----
  {
    const ushort_t* W3 = (const ushort_t*)(ws + OFF_W3BF);
    int pA[3];
    #pragma unroll
    for (int mt = 0; mt < 3; ++mt) {
      int m = mt*16 + col; if (m > 35) m = 35;
      int cell = m >> 2, sub = m & 3;
      int opy = cell / 3, opx = cell - opy*3;
      int y = 2*opy + (sub >> 1), xx = 2*opx + (sub & 1);
      pA[mt] = y*10 + xx;
    }
    f32x4 acc[3][2];
    #pragma unroll
    for (int mt = 0; mt < 3; ++mt) { acc[mt][0] = (f32x4)0.f; acc[mt][1] = (f32x4)0.f; }
    const int co0 = wv*16 + col, co1 = co0 + 64;
    #pragma unroll
    for (int ks = 0; ks < 18; ++ks) {
      const int t9 = ks >> 1, half = ks & 1, ch0 = half*32;
      const int toff = (t9/3)*10 + (t9%3);
      const int grp = half*4 + quad;
      int bidx = t9*8192 + ch0 + quad*8;
      short8 Bh0 = *(const short8*)(W3 + bidx + co0*64);
      short8 Bh1 = *(const short8*)(W3 + bidx + co1*64);
      short8 Bl0 = *(const short8*)(W3 + 73728 + bidx + co0*64);
      short8 Bl1 = *(const short8*)(W3 + 73728 + bidx + co1*64);
      #pragma unroll
      for (int mt = 0; mt < 3; ++mt) {
        int a = grp*640 + (pA[mt] + toff)*8;
        short8 Ah = *(const short8*)(A2h + a);
        short8 Al = *(const short8*)(A2l + a);
        acc[mt][0] = __builtin_amdgcn_mfma_f32_16x16x32_bf16(Al, Bh0, acc[mt][0], 0, 0, 0);
        acc[mt][0] = __builtin_amdgcn_mfma_f32_16x16x32_bf16(Ah, Bl0, acc[mt][0], 0, 0, 0);
        acc[mt][0] = __builtin_amdgcn_mfma_f32_16x16x32_bf16(Ah, Bh0, acc[mt][0], 0, 0, 0);
        acc[mt][1] = __builtin_amdgcn_mfma_f32_16x16x32_bf16(Al, Bh1, acc[mt][1], 0, 0, 0);
        acc[mt][1] = __builtin_amdgcn_mfma_f32_16x16x32_bf16(Ah, Bl1, acc[mt][1], 0, 0, 0);
        acc[mt][1] = __builtin_amdgcn_mfma_f32_16x16x32_bf16(Ah, Bh1, acc[mt][1], 0, 0, 0);
      }
    }
    ushort_t* hb_ = hhi + (size_t)b * 1152;
    ushort_t* lb_ = hlo + (size_t)b * 1152;
    #pragma unroll
    for (int mt = 0; mt < 3; ++mt) {
      int cell = mt*4 + quad;
      if (cell < 9) {
        #pragma unroll
        for (int j = 0; j < 2; ++j) {
          int ch = j ? co1 : co0;
          f32x4 a = acc[mt][j];
          float v = fmaxf(fmaxf(a.x, a.y), fmaxf(a.z, a.w)) + b3[ch];
          v = v > 0.f ? v : 0.f;
          ushort_t hb2 = f2bf(v);
          hb_[ch*9 + cell] = hb2;
          lb_[ch*9 + cell] = f2bf(v - bf2f(hb2));
        }
      }
    }
  }
}

// ---------------- fused enc_fc + argmin via MFMA bf16x3: 16 samples/block (unchanged) ----------
__global__ __launch_bounds__(256, 4) void vq_fc_argmin(
    const float* __restrict__ efb, const float* __restrict__ ws,
    const ushort_t* __restrict__ hhi, const ushort_t* __restrict__ hlo,
    int* __restrict__ ids)
{
  __shared__ float ZL[16*132];
  __shared__ float WVs[64];
  __shared__ int   WIs[64];
  const int t = threadIdx.x;
  const int sb = blockIdx.x * 16;
  const int lane = t & 63, wv = t >> 6;
  const int col = lane & 15, quad = lane >> 4;

  const ushort_t* EW  = (const ushort_t*)(ws + OFF_EWT);
  const ushort_t* CBB = (const ushort_t*)(ws + OFF_CT);

  f32x4 acc0 = (f32x4)0.f, acc1 = (f32x4)0.f;
  const size_t hrow = (size_t)(sb + col) * 1152 + quad*8;
  #pragma unroll 4
  for (int ks = 0; ks < 36; ++ks) {
    short8 Ah = *(const short8*)(hhi + hrow + ks*32);
    short8 Al = *(const short8*)(hlo + hrow + ks*32);
    int n0 = wv*32 + col, n1 = n0 + 16;
    const ushort_t* bp0 = EW + (ks*128 + n0)*32 + quad*8;
    const ushort_t* bp1 = EW + (ks*128 + n1)*32 + quad*8;
    short8 Bh0 = *(const short8*)(bp0);
    short8 Bl0 = *(const short8*)(bp0 + 147456);
    short8 Bh1 = *(const short8*)(bp1);
    short8 Bl1 = *(const short8*)(bp1 + 147456);
    acc0 = __builtin_amdgcn_mfma_f32_16x16x32_bf16(Al, Bh0, acc0, 0, 0, 0);
    acc0 = __builtin_amdgcn_mfma_f32_16x16x32_bf16(Ah, Bl0, acc0, 0, 0, 0);
    acc0 = __builtin_amdgcn_mfma_f32_16x16x32_bf16(Ah, Bh0, acc0, 0, 0, 0);
    acc1 = __builtin_amdgcn_mfma_f32_16x16x32_bf16(Al, Bh1, acc1, 0, 0, 0);
    acc1 = __builtin_amdgcn_mfma_f32_16x16x32_bf16(Ah, Bl1, acc1, 0, 0, 0);
    acc1 = __builtin_amdgcn_mfma_f32_16x16x32_bf16(Ah, Bh1, acc1, 0, 0, 0);
  }
  {
    int n0 = wv*32 + col, n1 = n0 + 16;
    float bs0 = efb[n0], bs1 = efb[n1];
    #pragma unroll
    for (int r = 0; r < 4; ++r) {
      int m = quad*4 + r;
      ZL[m*132 + n0] = acc0[r] + bs0;
      ZL[m*132 + n1] = acc1[r] + bs1;
    }
  }
  __syncthreads();

  short8 zAh[4], zAl[4];
  #pragma unroll
  for (int ks = 0; ks < 4; ++ks) {
    const float* zp = &ZL[col*132 + ks*32 + quad*8];
    float4 z0 = *(const float4*)zp;
    float4 z1 = *(const float4*)(zp + 4);
    float zv[8] = {z0.x, z0.y, z0.z, z0.w, z1.x, z1.y, z1.z, z1.w};
    ushort_t ph[8], pl[8];
    #pragma unroll
    for (int e = 0; e < 8; ++e) {
      ushort_t hb = f2bf(zv[e]);
      ph[e] = hb; pl[e] = f2bf(zv[e] - bf2f(hb));
    }
    zAh[ks] = *(const short8*)ph;
    zAl[ks] = *(const short8*)pl;
  }

  float bestv[4]; int besti[4];
  #pragma unroll
  for (int r = 0; r < 4; ++r) { bestv[r] = 3.4e38f; besti[r] = 0; }
  for (int c4 = 0; c4 < 4; ++c4) {
    f32x4 dacc[4];
    #pragma unroll
    for (int nn = 0; nn < 4; ++nn) dacc[nn] = (f32x4)0.f;
    #pragma unroll
    for (int ks = 0; ks < 4; ++ks) {
      #pragma unroll
      for (int nn = 0; nn < 4; ++nn) {
        int cw = (wv*16 + c4*4 + nn)*16 + col;
        const ushort_t* bp = CBB + (size_t)(ks*1024 + cw)*32 + quad*8;
        short8 Bh = *(const short8*)bp;
        short8 Bl = *(const short8*)(bp + 131072);
        dacc[nn] = __builtin_amdgcn_mfma_f32_16x16x32_bf16(zAl[ks], Bh, dacc[nn], 0, 0, 0);
        dacc[nn] = __builtin_amdgcn_mfma_f32_16x16x32_bf16(zAh[ks], Bl, dacc[nn], 0, 0, 0);
        dacc[nn] = __builtin_amdgcn_mfma_f32_16x16x32_bf16(zAh[ks], Bh, dacc[nn], 0, 0, 0);
      }
    }
    #pragma unroll
    for (int nn = 0; nn < 4; ++nn) {
      int cw = (wv*16 + c4*4 + nn)*16 + col;
      float ccv = ws[OFF_CC + cw];
      #pragma unroll
      for (int r = 0; r < 4; ++r) {
        float dist = ccv - 2.f*dacc[nn][r];
        if (dist < bestv[r]) { bestv[r] = dist; besti[r] = cw; }
      }
    }
  }

  #pragma unroll
  for (int r = 0; r < 4; ++r) {
    float v = bestv[r]; int ii = besti[r];
    #pragma unroll
    for (int off = 8; off >= 1; off >>= 1) {
      float v2 = __shfl_xor(v, off); int i2 = __shfl_xor(ii, off);
      if (v2 < v || (v2 == v && i2 < ii)) { v = v2; ii = i2; }
    }
    if (col == 0) {
      int m = quad*4 + r;
      WVs[wv*16 + m] = v; WIs[wv*16 + m] = ii;
    }
  }
  __syncthreads();
  if (t < 16) {
    float v = WVs[t]; int ii = WIs[t];
    #pragma unroll
    for (int w2 = 1; w2 < 4; ++w2) {
      float v2 = WVs[w2*16 + t]; int i2 = WIs[w2*16 + t];
      if (v2 < v || (v2 == v && i2 < ii)) { v = v2; ii = i2; }
    }
    ids[sb + t] = ii;
  }
}

// ---------------- decode table via MFMA D1/D2: 1 codeword per block ----------------
// POOL overlay: phase1 FA[25pix][136ch] hi/lo (3400 fl) + GA[8x8pix][72ch] hi/lo (4608 fl)
//               phase2 R2[14x14 pix][33 ch] fp32 (6468 fl)
__global__ __launch_bounds__(256, 4) void vq_dec_table(
    const float* __restrict__ codebook, const float* __restrict__ decb,
    const float* __restrict__ d1b, const float* __restrict__ d2b, const float* __restrict__ d3b,
    const float* __restrict__ ws, float* __restrict__ table)
{
  __shared__ float POOL[8008];
  __shared__ float PS[1536];
  __shared__ float ZQ[128];
  ushort_t* FAh = (ushort_t*)POOL;
  ushort_t* FAl = FAh + 3400;
  ushort_t* GAh = (ushort_t*)(POOL + 3400);
  ushort_t* GAl = GAh + 4608;
  float* R2 = POOL;

  const int t = threadIdx.x;
  const int cw = blockIdx.x;
  const int lane = t & 63, wv = t >> 6;
  const int col = lane & 15, quad = lane >> 4;

  for (int i = t; i < 8008; i += 256) POOL[i] = 0.f;
  if (t < 128) ZQ[t] = codebook[(size_t)cw*128 + t];
  __syncthreads();

  // ---- dec_fc (128->1152) VALU -> FA bf16 hi/lo (ch-last, ring-padded 5x5) ----
  #pragma unroll
  for (int p = 0; p < 5; ++p) {
    int j = t + p*256;
    if (j < 1152) {
      float a0 = decb[j];
      const float* wb = ws + OFF_DWT + j;
      #pragma unroll 4
      for (int k = 0; k < 128; ++k) a0 += wb[k*1152] * ZQ[k];
      int ci = j / 9, rem = j - ci*9;
      int pix = ((rem/3)+1)*5 + (rem%3) + 1;
      ushort_t hb = f2bf(a0);
      FAh[pix*136 + ci] = hb;
      FAl[pix*136 + ci] = f2bf(a0 - bf2f(hb));
    }
  }
  __syncthreads();

  // ---- D1 (128->64) MFMA: M=9(pad16), K=1152 (k=tap*128+ci), N=64; wave wv -> n-tile wv ----
  const ushort_t* BD1 = (const ushort_t*)(ws + OFF_BD1F);
  f32x4 acc1 = (f32x4)0.f;
  {
    const int m9 = col < 9 ? col : 8;
    const int oy = m9/3, ox = m9 - oy*3;
    const int co = wv*16 + col;
    #pragma unroll 4
    for (int ks = 0; ks < 36; ++ks) {
      int kb = ks*32 + quad*8;
      int tap = kb >> 7, ci0 = kb & 127;
      int pix = (oy + tap/3)*5 + ox + tap%3;
      short8 Ah = *(const short8*)(FAh + pix*136 + ci0);
      short8 Al = *(const short8*)(FAl + pix*136 + ci0);
      const ushort_t* bp = BD1 + co*1152 + kb;
      short8 Bh = *(const short8*)bp;
      short8 Bl = *(const short8*)(bp + 73728);
      acc1 = __builtin_amdgcn_mfma_f32_16x16x32_bf16(Al, Bh, acc1, 0, 0, 0);
      acc1 = __builtin_amdgcn_mfma_f32_16x16x32_bf16(Ah, Bl, acc1, 0, 0, 0);
      acc1 = __builtin_amdgcn_mfma_f32_16x16x32_bf16(Ah, Bh, acc1, 0, 0, 0);
    }
  }
  // D1 epilogue: bias+relu+upsample -> GA (disjoint from FA; no barrier needed before writes)
  {
    const int co = wv*16 + col;
    float bias = d1b[co];
    #pragma unroll
    for (int r = 0; r < 4; ++r) {
      int m = quad*4 + r;
      if (m < 9) {
        int oy = m/3, ox = m - oy*3;
        float v = acc1[r] + bias; v = v > 0.f ? v : 0.f;
        ushort_t hb = f2bf(v), lb = f2bf(v - bf2f(hb));
        int rbase = (2*oy+1)*8 + (2*ox+1);
        GAh[(rbase  )*72 + co] = hb; GAh[(rbase+1)*72 + co] = hb;
        GAh[(rbase+8)*72 + co] = hb; GAh[(rbase+9)*72 + co] = hb;
        GAl[(rbase  )*72 + co] = lb; GAl[(rbase+1)*72 + co] = lb;
        GAl[(rbase+8)*72 + co] = lb; GAl[(rbase+9)*72 + co] = lb;
      }
    }
  }
  __syncthreads();

  // ---- D2 (64->32) MFMA: M=36(pad48), K=576 (k=tap*64+ci), N=32; K-halved across wave pairs ----
  const ushort_t* BD2 = (const ushort_t*)(ws + OFF_BD2F);
  f32x4 acc2[3];
  acc2[0] = (f32x4)0.f; acc2[1] = (f32x4)0.f; acc2[2] = (f32x4)0.f;
  const int h = wv >> 1, js = (wv & 1)*3;
  for (int ks = h*9; ks < h*9 + 9; ++ks) {
    int kb = ks*32 + quad*8;
    int tap = kb >> 6, ci0 = kb & 63;
    int ty = tap/3, tx = tap - ty*3;
    #pragma unroll
    for (int jj = 0; jj < 3; ++jj) {
      int job = js + jj;
      int mt = job >> 1, nt = job & 1;
      int m = mt*16 + col; if (m > 35) m = 35;
      int oy = m/6, ox = m - oy*6;
      int pix = (oy+ty)*8 + ox+tx;
      short8 Ah = *(const short8*)(GAh + pix*72 + ci0);
      short8 Al = *(const short8*)(GAl + pix*72 + ci0);
      int co = nt*16 + col;
      const ushort_t* bp = BD2 + co*576 + kb;
      short8 Bh = *(const short8*)bp;
      short8 Bl = *(const short8*)(bp + 18432);
      acc2[jj] = __builtin_amdgcn_mfma_f32_16x16x32_bf16(Al, Bh, acc2[jj], 0, 0, 0);
      acc2[jj] = __builtin_amdgcn_mfma_f32_16x16x32_bf16(Ah, Bl, acc2[jj], 0, 0, 0);
      acc2[jj] = __builtin_amdgcn_mfma_f32_16x16x32_bf16(Ah, Bh, acc2[jj], 0, 0, 0);
    }
  }
  __syncthreads();                       // all GA/FA reads done
  if (h == 1) {
    #pragma unroll
    for (int jj = 0; jj < 3; ++jj) {
      int job = js + jj;
      #pragma unroll
      for (int r = 0; r < 4; ++r) PS[(job*64 + lane)*4 + r] = acc2[jj][r];
    }
  }
  for (int i = t; i < 6468; i += 256) R2[i] = 0.f;    // zero R2 (overlay; rings stay 0)
  __syncthreads();
  if (h == 0) {
    #pragma unroll
    for (int jj = 0; jj < 3; ++jj) {
      int job = js + jj;
      int mt = job >> 1, nt = job & 1;
      int co = nt*16 + col;
      float bias = d2b[co];
      #pragma unroll
      for (int r = 0; r < 4; ++r) {
        float v = acc2[jj][r] + PS[(job*64 + lane)*4 + r];
        int m = mt*16 + quad*4 + r;
        if (m < 36) {
          int oy = m/6, ox = m - oy*6;
          v += bias; v = v > 0.f ? v : 0.f;
          int rbase = (2*oy+1)*14 + (2*ox+1);
          R2[(rbase   )*33 + co] = v; R2[(rbase+ 1)*33 + co] = v;
          R2[(rbase+14)*33 + co] = v; R2[(rbase+15)*33 + co] = v;
        }
      }
    }
  }
  __syncthreads();

  // ---- D3 (32->1) VALU + relu + upsample -> table[cw] ----
  if (t < 144) {
    int yy = t / 12, xx = t - yy*12;
    const float* w3 = ws + OFF_D3R;
    float acc = d3b[0];
    #pragma unroll
    for (int dy = 0; dy < 3; ++dy)
      #pragma unroll
      for (int dx = 0; dx < 3; ++dx) {
        const float* rp = &R2[((yy+dy)*14 + xx+dx)*33];
        const float* wp = w3 + dy*3 + dx;
        #pragma unroll 8
        for (int ci = 0; ci < 32; ++ci) acc += rp[ci] * wp[ci*9];
      }
    float v = acc > 0.f ? acc : 0.f;
    float* ob = table + (size_t)cw * 576;
    int o0 = (2*yy)*24 + 2*xx;
    ob[o0] = v; ob[o0+1] = v; ob[o0+24] = v; ob[o0+25] = v;
  }
}

// ---------------- scatter: out[b] = table[ids[b]] ----------------
__global__ __launch_bounds__(256, 8) void vq_scatter(
    const float* __restrict__ table, const int* __restrict__ ids,
    float* __restrict__ out, int nvec)
{
  int idx = blockIdx.x * 256 + threadIdx.x;
  if (idx >= nvec) return;
  int b = idx / 144;
  int r = idx - b * 144;
  int cw = ids[b];
  ((float4*)out)[idx] = ((const float4*)(table + (size_t)cw * 576))[r];
}

extern "C" void kernel_launch(void* const* d_in, const int* in_sizes, int n_in,
                              void* d_out, int out_size, void* d_ws, size_t ws_size,
                              hipStream_t stream) {
  const float* x   = (const float*)d_in[0];
  const float* c1w = (const float*)d_in[1];
  const float* c1b = (const float*)d_in[2];
  const float* c2w = (const float*)d_in[3];
  const float* c2b = (const float*)d_in[4];
  const float* c3w = (const float*)d_in[5];
  const float* c3b = (const float*)d_in[6];
  const float* efw = (const float*)d_in[7];
  const float* efb = (const float*)d_in[8];
  const float* cb  = (const float*)d_in[9];
  const float* dfw = (const float*)d_in[10];
  const float* dfb = (const float*)d_in[11];
  const float* dw1 = (const float*)d_in[12];
  const float* db1 = (const float*)d_in[13];
  const float* dw2 = (const float*)d_in[14];
  const float* db2 = (const float*)d_in[15];
  const float* dw3 = (const float*)d_in[16];
  const float* db3 = (const float*)d_in[17];
  float* ws = (float*)d_ws;
  ushort_t* hhi  = (ushort_t*)(ws + OFF_H);
  ushort_t* hlo  = hhi + (size_t)8192*1152;
  float* table = ws + OFF_TABLE;
  int*   ids   = (int*)(ws + OFF_IDSN);
  float* outp = (float*)d_out;
  int B = in_sizes[0] / 576;

  vq_prep<<<(WS_WEIGHTS + 255) / 256, 256, 0, stream>>>(c1w, cb, dfw, dw3, ws);
  vq_prep2<<<(P2_N + 255) / 256, 256, 0, stream>>>(c2w, c3w, efw, cb, dw1, dw2, ws);
  vq_enc<<<B, 256, 0, stream>>>(x, c1b, c2b, c3b, ws, hhi, hlo);
  vq_fc_argmin<<<B/16, 256, 0, stream>>>(efb, ws, hhi, hlo, ids);
  vq_dec_table<<<1024, 256, 0, stream>>>(cb, dfb, db1, db2, db3, ws, table);
  int nvec = B * 144;
  vq_scatter<<<(nvec + 255) / 256, 256, 0, stream>>>(table, ids, outp, nvec);
}

// Round 8
// 627.424 us; speedup vs baseline: 1.2574x; 1.0093x over previous
//
#include <hip/hip_runtime.h>

typedef __attribute__((ext_vector_type(8))) short short8;
typedef __attribute__((ext_vector_type(4))) float f32x4;
typedef unsigned short ushort_t;
typedef unsigned int uint_t;

// ---------------- workspace layout (float offsets) ----------------
#define OFF_W1R   0
#define OFF_BD2F  288                   // D2 convT bf16 B-frags hi/lo [co32][k=tap*64+ci]
#define OFF_BD1F  18720                 // D1 convT bf16 B-frags hi/lo [co64][k=tap*128+ci]
#define OFF_EWT   (18720+73728)         // 92448   efw bf16 frags hi/lo [36ks][128n][32k]
#define OFF_CT    (92448+147456)        // 239904  codebook bf16 frags hi/lo [4ks][1024n][32k]
#define OFF_CC    (239904+131072)       // 370976  cc[1024]
#define OFF_DWT   (370976+1024)         // 372000  dwt[k][1152j]
#define OFF_D1R   (372000+147456)       // 519456  (unused)
#define OFF_D3R   (593184+18432)        // 611616  dct3 flipped [ci*9+tap]
#define WS_WEIGHTS (611616+288)         // 611904
#define OFF_W2BF  WS_WEIGHTS            // bf16 hi/lo conv2 w: [plane][tap][co64][ch32]
#define OFF_W3BF  (OFF_W2BF+18432)      // bf16 hi/lo conv3 w: [plane][tap][co128][ch64]
#define OFF_H     (OFF_W3BF+73728)      // h bf16 hi/lo planes [2][8192][1152] ushort
#define OFF_TABLE OFF_H                 // decoded table [1024][576] fp32 overlays dead h
#define OFF_IDSN  (OFF_H+8192*1152)     // ids [8192] int

__device__ __forceinline__ ushort_t f2bf(float v) {
  uint_t u = __float_as_uint(v);
  return (ushort_t)((u + 0x7FFFu + ((u >> 16) & 1u)) >> 16);
}
__device__ __forceinline__ float bf2f(ushort_t b) {
  return __uint_as_float(((uint_t)b) << 16);
}

// ---------------- merged prep: fp32 regions + all bf16 hi/lo frag regions ----------------
#define P2_N (92160 + 294912 + 262144 + 73728 + 18432)
#define PREP_N (WS_WEIGHTS + P2_N)
__global__ void vq_prep_all(const float* __restrict__ conv1_w, const float* __restrict__ conv2_w,
                            const float* __restrict__ conv3_w, const float* __restrict__ enc_fc_w,
                            const float* __restrict__ codebook, const float* __restrict__ dec_fc_w,
                            const float* __restrict__ dct1_w, const float* __restrict__ dct2_w,
                            const float* __restrict__ dct3_w, float* __restrict__ ws) {
  int i0 = blockIdx.x * blockDim.x + threadIdx.x;
  if (i0 >= PREP_N) return;
  if (i0 < WS_WEIGHTS) {
    int i = i0;
    if (i < OFF_BD2F) {
      int tap = i >> 5, co = i & 31;
      ws[i] = conv1_w[co*9 + tap];
    } else if (i < OFF_CC) {
      return;  // frag regions written below by other threads
    } else if (i < OFF_DWT) {
      int k = i - OFF_CC;
      float s = 0.f;
      for (int j = 0; j < 128; ++j) { float v = codebook[k*128+j]; s += v*v; }
      ws[i] = s;
    } else if (i < OFF_D1R) {
      int l = i - OFF_DWT;
      int j = l % 1152, k = l / 1152;
      ws[i] = dec_fc_w[j*128 + k];
    } else if (i < OFF_D3R) {
      return;
    } else {
      int l = i - OFF_D3R;
      int tap = l % 9, ci = l / 9;
      ws[i] = dct3_w[ci*9 + (8 - tap)];
    }
    return;
  }
  int i = i0 - WS_WEIGHTS;
  ushort_t* W2  = (ushort_t*)(ws + OFF_W2BF);
  ushort_t* W3  = (ushort_t*)(ws + OFF_W3BF);
  ushort_t* EW  = (ushort_t*)(ws + OFF_EWT);
  ushort_t* CB  = (ushort_t*)(ws + OFF_CT);
  ushort_t* BD1 = (ushort_t*)(ws + OFF_BD1F);
  ushort_t* BD2 = (ushort_t*)(ws + OFF_BD2F);
  if (i < 18432) {
    int tap = i >> 11, r = i & 2047, co = r >> 5, ch = r & 31;
    float v = conv2_w[(co*32 + ch)*9 + tap];
    ushort_t hb = f2bf(v);
    W2[i] = hb; W2[18432 + i] = f2bf(v - bf2f(hb));
  } else if (i < 92160) {
    int j = i - 18432;
    int tap = j >> 13, r = j & 8191, co = r >> 6, ch = r & 63;
    float v = conv3_w[(co*64 + ch)*9 + tap];
    ushort_t hb = f2bf(v);
    W3[j] = hb; W3[73728 + j] = f2bf(v - bf2f(hb));
  } else if (i < 387072) {
    int r = i - 92160;
    int p = r / 147456; r %= 147456;
    int kk = r & 31, n = (r >> 5) & 127, ks = r >> 12;
    float v = enc_fc_w[n*1152 + ks*32 + kk];
    ushort_t hb = f2bf(v);
    if (p == 0) EW[r] = hb; else EW[147456 + r] = f2bf(v - bf2f(hb));
  } else if (i < 649216) {
    int r = i - 387072;
    int p = r / 131072; r %= 131072;
    int kk = r & 31, cw = (r >> 5) & 1023, ks = r >> 15;
    float v = codebook[cw*128 + ks*32 + kk];
    ushort_t hb = f2bf(v);
    if (p == 0) CB[r] = hb; else CB[131072 + r] = f2bf(v - bf2f(hb));
  } else if (i < 722944) {
    int r = i - 649216;
    int co = r / 1152, k = r - co*1152;
    int tap = k >> 7, ci = k & 127;
    float v = dct1_w[(ci*64 + co)*9 + (8 - tap)];
    ushort_t hb = f2bf(v);
    BD1[r] = hb; BD1[73728 + r] = f2bf(v - bf2f(hb));
  } else {
    int r = i - 722944;
    int co = r / 576, k = r - co*576;
    int tap = k >> 6, ci = k & 63;
    float v = dct2_w[(ci*32 + co)*9 + (8 - tap)];
    ushort_t hb = f2bf(v);
    BD2[r] = hb; BD2[18432 + r] = f2bf(v - bf2f(hb));
  }
}

// ---------------- encoder: round-6 (401 µs) code; C3 overlaid into R0 -> 4 blocks/CU ----------
__global__ __launch_bounds__(256, 4) void vq_enc(
    const float* __restrict__ x,
    const float* __restrict__ b1, const float* __restrict__ b2, const float* __restrict__ b3,
    const float* __restrict__ ws, ushort_t* __restrict__ hhi, ushort_t* __restrict__ hlo)
{
  __shared__ ushort_t R0h[7840], R0l[7840];   // conv1-out [14][14][40]; later conv2-out [8][8][72]
  __shared__ float XT[624];                    // x [24][26] col-padded
  ushort_t* C3h = R0h;                         // overlay: conv2-out lives in R0 space
  ushort_t* C3l = R0l;
  const int t = threadIdx.x;
  const int b = blockIdx.x;

  for (int i = t; i < 3920; i += 256) { ((uint_t*)R0h)[i] = 0u; ((uint_t*)R0l)[i] = 0u; }
  const float* xb = x + (size_t)b * 576;
  for (int i = t; i < 624; i += 256) {
    int row = i / 26, col = i - row * 26;
    XT[i] = (col >= 1 && col <= 24) ? xb[row*24 + col - 1] : 0.f;
  }
  __syncthreads();

  // ---- conv1 (1->32) + relu + pool (vector fp32) ----
  {
    int co = t & 31, g = t >> 5, gy = g >> 1, gx = g & 1;
    float w[9];
    #pragma unroll
    for (int k = 0; k < 9; ++k) w[k] = ws[OFF_W1R + k*32 + co];
    float bias = b1[co];
    #pragma unroll
    for (int pr = 0; pr < 3; ++pr) {
      int Y = gy*6 + pr*2;
      float a0[12], a1[12];
      #pragma unroll
      for (int i = 0; i < 12; ++i) { a0[i] = 0.f; a1[i] = 0.f; }
      #pragma unroll
      for (int wy = 0; wy < 4; ++wy) {
        int ry = Y - 1 + wy;
        if (ry < 0 || ry > 23) continue;
        const float2* rp = (const float2*)&XT[ry*26 + gx*12];
        float r[14];
        #pragma unroll
        for (int k = 0; k < 7; ++k) { float2 p = rp[k]; r[2*k] = p.x; r[2*k+1] = p.y; }
        if (wy < 3) {
          #pragma unroll
          for (int xx = 0; xx < 12; ++xx)
            #pragma unroll
            for (int dx = 0; dx < 3; ++dx) a0[xx] += r[xx+dx] * w[wy*3+dx];
        }
        if (wy >= 1) {
          #pragma unroll
          for (int xx = 0; xx < 12; ++xx)
            #pragma unroll
            for (int dx = 0; dx < 3; ++dx) a1[xx] += r[xx+dx] * w[(wy-1)*3+dx];
        }
      }
      #pragma unroll
      for (int pc = 0; pc < 6; ++pc) {
        float m = fmaxf(fmaxf(a0[2*pc], a0[2*pc+1]), fmaxf(a1[2*pc], a1[2*pc+1]));
        float v = m + bias; v = v > 0.f ? v : 0.f;
        int row = gy*3 + pr, colp = gx*6 + pc;
        int addr = ((row+1)*14 + (colp+1))*40 + co;
        ushort_t hb = f2bf(v);
        R0h[addr] = hb;
        R0l[addr] = f2bf(v - bf2f(hb));
      }
    }
  }
  __syncthreads();

  const int lane = t & 63, quad = lane >> 4, col = lane & 15;
  const int wv = t >> 6;

  // ---- conv2 (32->64, K=288) MFMA, M=144 pool-grouped (+pad to 160) ----
  {
    const int h = wv & 1, p = wv >> 1;
    const ushort_t* W2 = (const ushort_t*)(ws + OFF_W2BF);
    int baseA[5];
    #pragma unroll
    for (int mi = 0; mi < 5; ++mi) {
      int m = (h*5 + mi)*16 + col; if (m > 143) m = 143;
      int cell = m >> 2, sub = m & 3;
      int opy = cell / 6, opx = cell - opy*6;
      int y = 2*opy + (sub >> 1), xx = 2*opx + (sub & 1);
      baseA[mi] = (y*14 + xx)*40 + quad*8;
    }
    f32x4 acc[5][2];
    #pragma unroll
    for (int mi = 0; mi < 5; ++mi) { acc[mi][0] = (f32x4)0.f; acc[mi][1] = (f32x4)0.f; }
    const int co0 = p*32 + col, co1 = co0 + 16;
    #pragma unroll
    for (int t9 = 0; t9 < 9; ++t9) {
      const int TAPOFF = ((t9/3)*14 + (t9%3))*40;
      int bidx = t9*2048 + quad*8;
      short8 Bh0 = *(const short8*)(W2 + bidx + co0*32);
      short8 Bh1 = *(const short8*)(W2 + bidx + co1*32);
      short8 Bl0 = *(const short8*)(W2 + 18432 + bidx + co0*32);
      short8 Bl1 = *(const short8*)(W2 + 18432 + bidx + co1*32);
      #pragma unroll
      for (int mi = 0; mi < 5; ++mi) {
        int a = baseA[mi] + TAPOFF;
        short8 Ah = *(const short8*)(R0h + a);
        short8 Al = *(const short8*)(R0l + a);
        acc[mi][0] = __builtin_amdgcn_mfma_f32_16x16x32_bf16(Al, Bh0, acc[mi][0], 0, 0, 0);
        acc[mi][0] = __builtin_amdgcn_mfma_f32_16x16x32_bf16(Ah, Bl0, acc[mi][0], 0, 0, 0);
        acc[mi][0] = __builtin_amdgcn_mfma_f32_16x16x32_bf16(Ah, Bh0, acc[mi][0], 0, 0, 0);
        acc[mi][1] = __builtin_amdgcn_mfma_f32_16x16x32_bf16(Al, Bh1, acc[mi][1], 0, 0, 0);
        acc[mi][1] = __builtin_amdgcn_mfma_f32_16x16x32_bf16(Ah, Bl1, acc[mi][1], 0, 0, 0);
        acc[mi][1] = __builtin_amdgcn_mfma_f32_16x16x32_bf16(Ah, Bh1, acc[mi][1], 0, 0, 0);
      }
    }
    __syncthreads();                 // all R0 reads done — safe to overlay C3
    for (int i = t; i < 2304; i += 256) { ((uint_t*)C3h)[i] = 0u; ((uint_t*)C3l)[i] = 0u; }
    __syncthreads();                 // zeros visible
    #pragma unroll
    for (int mi = 0; mi < 5; ++mi) {
      int cell = (h*5 + mi)*4 + quad;
      if (cell < 36) {
        int opy = cell / 6, opx = cell - opy*6;
        int wa = ((opy+1)*8 + (opx+1))*72;
        #pragma unroll
        for (int j = 0; j < 2; ++j) {
          int ch = j ? co1 : co0;
          f32x4 a = acc[mi][j];
          float v = fmaxf(fmaxf(a.x, a.y), fmaxf(a.z, a.w)) + b2[ch];
          v = v > 0.f ? v : 0.f;
          ushort_t hb = f2bf(v);
          C3h[wa + ch] = hb;
          C3l[wa + ch] = f2bf(v - bf2f(hb));
        }
      }
    }
  }
  __syncthreads();

  // ---- conv3 (64->128, K=576) MFMA ----
  {
    const ushort_t* W3 = (const ushort_t*)(ws + OFF_W3BF);
    int baseA[3];
    #pragma unroll
    for (int mt = 0; mt < 3; ++mt) {
      int m = mt*16 + col; if (m > 35) m = 35;
      int cell = m >> 2, sub = m & 3;
      int opy = cell / 3, opx = cell - opy*3;
      int y = 2*opy + (sub >> 1), xx = 2*opx + (sub & 1);
      baseA[mt] = (y*8 + xx)*72 + quad*8;
    }
    f32x4 acc[3][2];
    #pragma unroll
    for (int mt = 0; mt < 3; ++mt) { acc[mt][0] = (f32x4)0.f; acc[mt][1] = (f32x4)0.f; }
    const int co0 = wv*16 + col, co1 = co0 + 64;
    #pragma unroll
    for (int ks = 0; ks < 18; ++ks) {
      const int t9 = ks >> 1, ch0 = (ks & 1)*32;
      const int TAPOFF = ((t9/3)*8 + (t9%3))*72;
      int bidx = t9*8192 + ch0 + quad*8;
      short8 Bh0 = *(const short8*)(W3 + bidx + co0*64);
      short8 Bh1 = *(const short8*)(W3 + bidx + co1*64);
      short8 Bl0 = *(const short8*)(W3 + 73728 + bidx + co0*64);
      short8 Bl1 = *(const short8*)(W3 + 73728 + bidx + co1*64);
      #pragma unroll
      for (int mt = 0; mt < 3; ++mt) {
        int a = baseA[mt] + TAPOFF + ch0;
        short8 Ah = *(const short8*)(C3h + a);
        short8 Al = *(const short8*)(C3l + a);
        acc[mt][0] = __builtin_amdgcn_mfma_f32_16x16x32_bf16(Al, Bh0, acc[mt][0], 0, 0, 0);
        acc[mt][0] = __builtin_amdgcn_mfma_f32_16x16x32_bf16(Ah, Bl0, acc[mt][0], 0, 0, 0);
        acc[mt][0] = __builtin_amdgcn_mfma_f32_16x16x32_bf16(Ah, Bh0, acc[mt][0], 0, 0, 0);
        acc[mt][1] = __builtin_amdgcn_mfma_f32_16x16x32_bf16(Al, Bh1, acc[mt][1], 0, 0, 0);
        acc[mt][1] = __builtin_amdgcn_mfma_f32_16x16x32_bf16(Ah, Bl1, acc[mt][1], 0, 0, 0);
        acc[mt][1] = __builtin_amdgcn_mfma_f32_16x16x32_bf16(Ah, Bh1, acc[mt][1], 0, 0, 0);
      }
    }
    ushort_t* hb_ = hhi + (size_t)b * 1152;
    ushort_t* lb_ = hlo + (size_t)b * 1152;
    #pragma unroll
    for (int mt = 0; mt < 3; ++mt) {
      int cell = mt*4 + quad;
      if (cell < 9) {
        #pragma unroll
        for (int j = 0; j < 2; ++j) {
          int ch = j ? co1 : co0;
          f32x4 a = acc[mt][j];
          float v = fmaxf(fmaxf(a.x, a.y), fmaxf(a.z, a.w)) + b3[ch];
          v = v > 0.f ? v : 0.f;
          ushort_t hb2 = f2bf(v);
          hb_[ch*9 + cell] = hb2;
          lb_[ch*9 + cell] = f2bf(v - bf2f(hb2));
        }
      }
    }
  }
}

// ---------------- fused enc_fc + argmin via MFMA bf16x3: 16 samples/block ----------------
__global__ __launch_bounds__(256, 4) void vq_fc_argmin(
    const float* __restrict__ efb, const float* __restrict__ ws,
    const ushort_t* __restrict__ hhi, const ushort_t* __restrict__ hlo,
    int* __restrict__ ids)
{
  __shared__ float ZL[16*132];
  __shared__ float WVs[64];
  __shared__ int   WIs[64];
  const int t = threadIdx.x;
  const int sb = blockIdx.x * 16;
  const int lane = t & 63, wv = t >> 6;
  const int col = lane & 15, quad = lane >> 4;

  const ushort_t* EW  = (const ushort_t*)(ws + OFF_EWT);
  const ushort_t* CBB = (const ushort_t*)(ws + OFF_CT);

  f32x4 acc0 = (f32x4)0.f, acc1 = (f32x4)0.f;
  const size_t hrow = (size_t)(sb + col) * 1152 + quad*8;
  #pragma unroll 4
  for (int ks = 0; ks < 36; ++ks) {
    short8 Ah = *(const short8*)(hhi + hrow + ks*32);
    short8 Al = *(const short8*)(hlo + hrow + ks*32);
    int n0 = wv*32 + col, n1 = n0 + 16;
    const ushort_t* bp0 = EW + (ks*128 + n0)*32 + quad*8;
    const ushort_t* bp1 = EW + (ks*128 + n1)*32 + quad*8;
    short8 Bh0 = *(const short8*)(bp0);
    short8 Bl0 = *(const short8*)(bp0 + 147456);
    short8 Bh1 = *(const short8*)(bp1);
    short8 Bl1 = *(const short8*)(bp1 + 147456);
    acc0 = __builtin_amdgcn_mfma_f32_16x16x32_bf16(Al, Bh0, acc0, 0, 0, 0);
    acc0 = __builtin_amdgcn_mfma_f32_16x16x32_bf16(Ah, Bl0, acc0, 0, 0, 0);
    acc0 = __builtin_amdgcn_mfma_f32_16x16x32_bf16(Ah, Bh0, acc0, 0, 0, 0);
    acc1 = __builtin_amdgcn_mfma_f32_16x16x32_bf16(Al, Bh1, acc1, 0, 0, 0);
    acc1 = __builtin_amdgcn_mfma_f32_16x16x32_bf16(Ah, Bl1, acc1, 0, 0, 0);
    acc1 = __builtin_amdgcn_mfma_f32_16x16x32_bf16(Ah, Bh1, acc1, 0, 0, 0);
  }
  {
    int n0 = wv*32 + col, n1 = n0 + 16;
    float bs0 = efb[n0], bs1 = efb[n1];
    #pragma unroll
    for (int r = 0; r < 4; ++r) {
      int m = quad*4 + r;
      ZL[m*132 + n0] = acc0[r] + bs0;
      ZL[m*132 + n1] = acc1[r] + bs1;
    }
  }
  __syncthreads();

  short8 zAh[4], zAl[4];
  #pragma unroll
  for (int ks = 0; ks < 4; ++ks) {
    const float* zp = &ZL[col*132 + ks*32 + quad*8];
    float4 z0 = *(const float4*)zp;
    float4 z1 = *(const float4*)(zp + 4);
    float zv[8] = {z0.x, z0.y, z0.z, z0.w, z1.x, z1.y, z1.z, z1.w};
    ushort_t ph[8], pl[8];
    #pragma unroll
    for (int e = 0; e < 8; ++e) {
      ushort_t hb = f2bf(zv[e]);
      ph[e] = hb; pl[e] = f2bf(zv[e] - bf2f(hb));
    }
    zAh[ks] = *(const short8*)ph;
    zAl[ks] = *(const short8*)pl;
  }

  float bestv[4]; int besti[4];
  #pragma unroll
  for (int r = 0; r < 4; ++r) { bestv[r] = 3.4e38f; besti[r] = 0; }
  for (int c4 = 0; c4 < 4; ++c4) {
    f32x4 dacc[4];
    #pragma unroll
    for (int nn = 0; nn < 4; ++nn) dacc[nn] = (f32x4)0.f;
    #pragma unroll
    for (int ks = 0; ks < 4; ++ks) {
      #pragma unroll
      for (int nn = 0; nn < 4; ++nn) {
        int cw = (wv*16 + c4*4 + nn)*16 + col;
        const ushort_t* bp = CBB + (size_t)(ks*1024 + cw)*32 + quad*8;
        short8 Bh = *(const short8*)bp;
        short8 Bl = *(const short8*)(bp + 131072);
        dacc[nn] = __builtin_amdgcn_mfma_f32_16x16x32_bf16(zAl[ks], Bh, dacc[nn], 0, 0, 0);
        dacc[nn] = __builtin_amdgcn_mfma_f32_16x16x32_bf16(zAh[ks], Bl, dacc[nn], 0, 0, 0);
        dacc[nn] = __builtin_amdgcn_mfma_f32_16x16x32_bf16(zAh[ks], Bh, dacc[nn], 0, 0, 0);
      }
    }
    #pragma unroll
    for (int nn = 0; nn < 4; ++nn) {
      int cw = (wv*16 + c4*4 + nn)*16 + col;
      float ccv = ws[OFF_CC + cw];
      #pragma unroll
      for (int r = 0; r < 4; ++r) {
        float dist = ccv - 2.f*dacc[nn][r];
        if (dist < bestv[r]) { bestv[r] = dist; besti[r] = cw; }
      }
    }
  }

  #pragma unroll
  for (int r = 0; r < 4; ++r) {
    float v = bestv[r]; int ii = besti[r];
    #pragma unroll
    for (int off = 8; off >= 1; off >>= 1) {
      float v2 = __shfl_xor(v, off); int i2 = __shfl_xor(ii, off);
      if (v2 < v || (v2 == v && i2 < ii)) { v = v2; ii = i2; }
    }
    if (col == 0) {
      int m = quad*4 + r;
      WVs[wv*16 + m] = v; WIs[wv*16 + m] = ii;
    }
  }
  __syncthreads();
  if (t < 16) {
    float v = WVs[t]; int ii = WIs[t];
    #pragma unroll
    for (int w2 = 1; w2 < 4; ++w2) {
      float v2 = WVs[w2*16 + t]; int i2 = WIs[w2*16 + t];
      if (v2 < v || (v2 == v && i2 < ii)) { v = v2; ii = i2; }
    }
    ids[sb + t] = ii;
  }
}

// ---------------- decode table via MFMA D1/D2 (round-7, verified): 1 codeword/block --------
__global__ __launch_bounds__(256, 4) void vq_dec_table(
    const float* __restrict__ codebook, const float* __restrict__ decb,
    const float* __restrict__ d1b, const float* __restrict__ d2b, const float* __restrict__ d3b,
    const float* __restrict__ ws, float* __restrict__ table)
{
  __shared__ float POOL[8008];
  __shared__ float PS[1536];
  __shared__ float ZQ[128];
  ushort_t* FAh = (ushort_t*)POOL;
  ushort_t* FAl = FAh + 3400;
  ushort_t* GAh = (ushort_t*)(POOL + 3400);
  ushort_t* GAl = GAh + 4608;
  float* R2 = POOL;

  const int t = threadIdx.x;
  const int cw = blockIdx.x;
  const int lane = t & 63, wv = t >> 6;
  const int col = lane & 15, quad = lane >> 4;

  for (int i = t; i < 8008; i += 256) POOL[i] = 0.f;
  if (t < 128) ZQ[t] = codebook[(size_t)cw*128 + t];
  __syncthreads();

  #pragma unroll
  for (int p = 0; p < 5; ++p) {
    int j = t + p*256;
    if (j < 1152) {
      float a0 = decb[j];
      const float* wb = ws + OFF_DWT + j;
      #pragma unroll 4
      for (int k = 0; k < 128; ++k) a0 += wb[k*1152] * ZQ[k];
      int ci = j / 9, rem = j - ci*9;
      int pix = ((rem/3)+1)*5 + (rem%3) + 1;
      ushort_t hb = f2bf(a0);
      FAh[pix*136 + ci] = hb;
      FAl[pix*136 + ci] = f2bf(a0 - bf2f(hb));
    }
  }
  __syncthreads();

  const ushort_t* BD1 = (const ushort_t*)(ws + OFF_BD1F);
  f32x4 acc1 = (f32x4)0.f;
  {
    const int m9 = col < 9 ? col : 8;
    const int oy = m9/3, ox = m9 - oy*3;
    const int co = wv*16 + col;
    #pragma unroll 4
    for (int ks = 0; ks < 36; ++ks) {
      int kb = ks*32 + quad*8;
      int tap = kb >> 7, ci0 = kb & 127;
      int pix = (oy + tap/3)*5 + ox + tap%3;
      short8 Ah = *(const short8*)(FAh + pix*136 + ci0);
      short8 Al = *(const short8*)(FAl + pix*136 + ci0);
      const ushort_t* bp = BD1 + co*1152 + kb;
      short8 Bh = *(const short8*)bp;
      short8 Bl = *(const short8*)(bp + 73728);
      acc1 = __builtin_amdgcn_mfma_f32_16x16x32_bf16(Al, Bh, acc1, 0, 0, 0);
      acc1 = __builtin_amdgcn_mfma_f32_16x16x32_bf16(Ah, Bl, acc1, 0, 0, 0);
      acc1 = __builtin_amdgcn_mfma_f32_16x16x32_bf16(Ah, Bh, acc1, 0, 0, 0);
    }
  }
  {
    const int co = wv*16 + col;
    float bias = d1b[co];
    #pragma unroll
    for (int r = 0; r < 4; ++r) {
      int m = quad*4 + r;
      if (m < 9) {
        int oy = m/3, ox = m - oy*3;
        float v = acc1[r] + bias; v = v > 0.f ? v : 0.f;
        ushort_t hb = f2bf(v), lb = f2bf(v - bf2f(hb));
        int rbase = (2*oy+1)*8 + (2*ox+1);
        GAh[(rbase  )*72 + co] = hb; GAh[(rbase+1)*72 + co] = hb;
        GAh[(rbase+8)*72 + co] = hb; GAh[(rbase+9)*72 + co] = hb;
        GAl[(rbase  )*72 + co] = lb; GAl[(rbase+1)*72 + co] = lb;
        GAl[(rbase+8)*72 + co] = lb; GAl[(rbase+9)*72 + co] = lb;
      }
    }
  }
  __syncthreads();

  const ushort_t* BD2 = (const ushort_t*)(ws + OFF_BD2F);
  f32x4 acc2[3];
  acc2[0] = (f32x4)0.f; acc2[1] = (f32x4)0.f; acc2[2] = (f32x4)0.f;
  const int h = wv >> 1, js = (wv & 1)*3;
  for (int ks = h*9; ks < h*9 + 9; ++ks) {
    int kb = ks*32 + quad*8;
    int tap = kb >> 6, ci0 = kb & 63;
    int ty = tap/3, tx = tap - ty*3;
    #pragma unroll
    for (int jj = 0; jj < 3; ++jj) {
      int job = js + jj;
      int mt = job >> 1, nt = job & 1;
      int m = mt*16 + col; if (m > 35) m = 35;
      int oy = m/6, ox = m - oy*6;
      int pix = (oy+ty)*8 + ox+tx;
      short8 Ah = *(const short8*)(GAh + pix*72 + ci0);
      short8 Al = *(const short8*)(GAl + pix*72 + ci0);
      int co = nt*16 + col;
      const ushort_t* bp = BD2 + co*576 + kb;
      short8 Bh = *(const short8*)bp;
      short8 Bl = *(const short8*)(bp + 18432);
      acc2[jj] = __builtin_amdgcn_mfma_f32_16x16x32_bf16(Al, Bh, acc2[jj], 0, 0, 0);
      acc2[jj] = __builtin_amdgcn_mfma_f32_16x16x32_bf16(Ah, Bl, acc2[jj], 0, 0, 0);
      acc2[jj] = __builtin_amdgcn_mfma_f32_16x16x32_bf16(Ah, Bh, acc2[jj], 0, 0, 0);
    }
  }
  __syncthreads();
  if (h == 1) {
    #pragma unroll
    for (int jj = 0; jj < 3; ++jj) {
      int job = js + jj;
      #pragma unroll
      for (int r = 0; r < 4; ++r) PS[(job*64 + lane)*4 + r] = acc2[jj][r];
    }
  }
  for (int i = t; i < 6468; i += 256) R2[i] = 0.f;
  __syncthreads();
  if (h == 0) {
    #pragma unroll
    for (int jj = 0; jj < 3; ++jj) {
      int job = js + jj;
      int mt = job >> 1, nt = job & 1;
      int co = nt*16 + col;
      float bias = d2b[co];
      #pragma unroll
      for (int r = 0; r < 4; ++r) {
        float v = acc2[jj][r] + PS[(job*64 + lane)*4 + r];
        int m = mt*16 + quad*4 + r;
        if (m < 36) {
          int oy = m/6, ox = m - oy*6;
          v += bias; v = v > 0.f ? v : 0.f;
          int rbase = (2*oy+1)*14 + (2*ox+1);
          R2[(rbase   )*33 + co] = v; R2[(rbase+ 1)*33 + co] = v;
          R2[(rbase+14)*33 + co] = v; R2[(rbase+15)*33 + co] = v;
        }
      }
    }
  }
  __syncthreads();

  if (t < 144) {
    int yy = t / 12, xx = t - yy*12;
    const float* w3 = ws + OFF_D3R;
    float acc = d3b[0];
    #pragma unroll
    for (int dy = 0; dy < 3; ++dy)
      #pragma unroll
      for (int dx = 0; dx < 3; ++dx) {
        const float* rp = &R2[((yy+dy)*14 + xx+dx)*33];
        const float* wp = w3 + dy*3 + dx;
        #pragma unroll 8
        for (int ci = 0; ci < 32; ++ci) acc += rp[ci] * wp[ci*9];
      }
    float v = acc > 0.f ? acc : 0.f;
    float* ob = table + (size_t)cw * 576;
    int o0 = (2*yy)*24 + 2*xx;
    ob[o0] = v; ob[o0+1] = v; ob[o0+24] = v; ob[o0+25] = v;
  }
}

// ---------------- scatter: out[b] = table[ids[b]] ----------------
__global__ __launch_bounds__(256, 8) void vq_scatter(
    const float* __restrict__ table, const int* __restrict__ ids,
    float* __restrict__ out, int nvec)
{
  int idx = blockIdx.x * 256 + threadIdx.x;
  if (idx >= nvec) return;
  int b = idx / 144;
  int r = idx - b * 144;
  int cw = ids[b];
  ((float4*)out)[idx] = ((const float4*)(table + (size_t)cw * 576))[r];
}

extern "C" void kernel_launch(void* const* d_in, const int* in_sizes, int n_in,
                              void* d_out, int out_size, void* d_ws, size_t ws_size,
                              hipStream_t stream) {
  const float* x   = (const float*)d_in[0];
  const float* c1w = (const float*)d_in[1];
  const float* c1b = (const float*)d_in[2];
  const float* c2w = (const float*)d_in[3];
  const float* c2b = (const float*)d_in[4];
  const float* c3w = (const float*)d_in[5];
  const float* c3b = (const float*)d_in[6];
  const float* efw = (const float*)d_in[7];
  const float* efb = (const float*)d_in[8];
  const float* cb  = (const float*)d_in[9];
  const float* dfw = (const float*)d_in[10];
  const float* dfb = (const float*)d_in[11];
  const float* dw1 = (const float*)d_in[12];
  const float* db1 = (const float*)d_in[13];
  const float* dw2 = (const float*)d_in[14];
  const float* db2 = (const float*)d_in[15];
  const float* dw3 = (const float*)d_in[16];
  const float* db3 = (const float*)d_in[17];
  float* ws = (float*)d_ws;
  ushort_t* hhi  = (ushort_t*)(ws + OFF_H);
  ushort_t* hlo  = hhi + (size_t)8192*1152;
  float* table = ws + OFF_TABLE;
  int*   ids   = (int*)(ws + OFF_IDSN);
  float* outp = (float*)d_out;
  int B = in_sizes[0] / 576;

  vq_prep_all<<<(PREP_N + 255) / 256, 256, 0, stream>>>(c1w, c2w, c3w, efw, cb, dfw, dw1, dw2, dw3, ws);
  vq_enc<<<B, 256, 0, stream>>>(x, c1b, c2b, c3b, ws, hhi, hlo);
  vq_fc_argmin<<<B/16, 256, 0, stream>>>(efb, ws, hhi, hlo, ids);
  vq_dec_table<<<1024, 256, 0, stream>>>(cb, dfb, db1, db2, db3, ws, table);
  int nvec = B * 144;
  vq_scatter<<<(nvec + 255) / 256, 256, 0, stream>>>(table, ids, outp, nvec);
}

// Round 9
// 605.448 us; speedup vs baseline: 1.3030x; 1.0363x over previous
//
#include <hip/hip_runtime.h>

typedef __attribute__((ext_vector_type(8))) short short8;
typedef __attribute__((ext_vector_type(4))) float f32x4;
typedef unsigned short ushort_t;
typedef unsigned int uint_t;

// ---------------- workspace layout (float offsets) ----------------
#define OFF_W1R   0
#define OFF_BD2F  288                   // D2 convT bf16 B-frags hi/lo [co32][k=tap*64+ci]
#define OFF_BD1F  18720                 // D1 convT bf16 B-frags hi/lo [co64][k=tap*128+ci]
#define OFF_EWT   (18720+73728)         // 92448   efw bf16 frags hi/lo [36ks][128n][32k]
#define OFF_CT    (92448+147456)        // 239904  codebook bf16 frags hi/lo [4ks][1024n][32k]
#define OFF_CC    (239904+131072)       // 370976  cc[1024]
#define OFF_DWT   (370976+1024)         // 372000  dwt[k][1152j]
#define OFF_D1R   (372000+147456)       // 519456  (unused)
#define OFF_D3R   (593184+18432)        // 611616  dct3 flipped [ci*9+tap]
#define WS_WEIGHTS (611616+288)         // 611904
#define OFF_W2BF  WS_WEIGHTS            // bf16 hi/lo conv2 w: [plane][tap][co64][ch32]
#define OFF_W3BF  (OFF_W2BF+18432)      // bf16 hi/lo conv3 w: [plane][tap][co128][ch64]
#define OFF_H     (OFF_W3BF+73728)      // h bf16 hi/lo planes [2][8192][1152] ushort
#define OFF_TABLE (OFF_H + 8192*1152)   // decoded table [1024][576] fp32 (separate from h now)

__device__ __forceinline__ ushort_t f2bf(float v) {
  uint_t u = __float_as_uint(v);
  return (ushort_t)((u + 0x7FFFu + ((u >> 16) & 1u)) >> 16);
}
__device__ __forceinline__ float bf2f(ushort_t b) {
  return __uint_as_float(((uint_t)b) << 16);
}

// ---------------- merged prep ----------------
#define P2_N (92160 + 294912 + 262144 + 73728 + 18432)
#define PREP_N (WS_WEIGHTS + P2_N)
__global__ void vq_prep_all(const float* __restrict__ conv1_w, const float* __restrict__ conv2_w,
                            const float* __restrict__ conv3_w, const float* __restrict__ enc_fc_w,
                            const float* __restrict__ codebook, const float* __restrict__ dec_fc_w,
                            const float* __restrict__ dct1_w, const float* __restrict__ dct2_w,
                            const float* __restrict__ dct3_w, float* __restrict__ ws) {
  int i0 = blockIdx.x * blockDim.x + threadIdx.x;
  if (i0 >= PREP_N) return;
  if (i0 < WS_WEIGHTS) {
    int i = i0;
    if (i < OFF_BD2F) {
      int tap = i >> 5, co = i & 31;
      ws[i] = conv1_w[co*9 + tap];
    } else if (i < OFF_CC) {
      return;
    } else if (i < OFF_DWT) {
      int k = i - OFF_CC;
      float s = 0.f;
      for (int j = 0; j < 128; ++j) { float v = codebook[k*128+j]; s += v*v; }
      ws[i] = s;
    } else if (i < OFF_D1R) {
      int l = i - OFF_DWT;
      int j = l % 1152, k = l / 1152;
      ws[i] = dec_fc_w[j*128 + k];
    } else if (i < OFF_D3R) {
      return;
    } else {
      int l = i - OFF_D3R;
      int tap = l % 9, ci = l / 9;
      ws[i] = dct3_w[ci*9 + (8 - tap)];
    }
    return;
  }
  int i = i0 - WS_WEIGHTS;
  ushort_t* W2  = (ushort_t*)(ws + OFF_W2BF);
  ushort_t* W3  = (ushort_t*)(ws + OFF_W3BF);
  ushort_t* EW  = (ushort_t*)(ws + OFF_EWT);
  ushort_t* CB  = (ushort_t*)(ws + OFF_CT);
  ushort_t* BD1 = (ushort_t*)(ws + OFF_BD1F);
  ushort_t* BD2 = (ushort_t*)(ws + OFF_BD2F);
  if (i < 18432) {
    int tap = i >> 11, r = i & 2047, co = r >> 5, ch = r & 31;
    float v = conv2_w[(co*32 + ch)*9 + tap];
    ushort_t hb = f2bf(v);
    W2[i] = hb; W2[18432 + i] = f2bf(v - bf2f(hb));
  } else if (i < 92160) {
    int j = i - 18432;
    int tap = j >> 13, r = j & 8191, co = r >> 6, ch = r & 63;
    float v = conv3_w[(co*64 + ch)*9 + tap];
    ushort_t hb = f2bf(v);
    W3[j] = hb; W3[73728 + j] = f2bf(v - bf2f(hb));
  } else if (i < 387072) {
    int r = i - 92160;
    int p = r / 147456; r %= 147456;
    int kk = r & 31, n = (r >> 5) & 127, ks = r >> 12;
    float v = enc_fc_w[n*1152 + ks*32 + kk];
    ushort_t hb = f2bf(v);
    if (p == 0) EW[r] = hb; else EW[147456 + r] = f2bf(v - bf2f(hb));
  } else if (i < 649216) {
    int r = i - 387072;
    int p = r / 131072; r %= 131072;
    int kk = r & 31, cw = (r >> 5) & 1023, ks = r >> 15;
    float v = codebook[cw*128 + ks*32 + kk];
    ushort_t hb = f2bf(v);
    if (p == 0) CB[r] = hb; else CB[131072 + r] = f2bf(v - bf2f(hb));
  } else if (i < 722944) {
    int r = i - 649216;
    int co = r / 1152, k = r - co*1152;
    int tap = k >> 7, ci = k & 127;
    float v = dct1_w[(ci*64 + co)*9 + (8 - tap)];
    ushort_t hb = f2bf(v);
    BD1[r] = hb; BD1[73728 + r] = f2bf(v - bf2f(hb));
  } else {
    int r = i - 722944;
    int co = r / 576, k = r - co*576;
    int tap = k >> 6, ci = k & 63;
    float v = dct2_w[(ci*32 + co)*9 + (8 - tap)];
    ushort_t hb = f2bf(v);
    BD2[r] = hb; BD2[18432 + r] = f2bf(v - bf2f(hb));
  }
}

// ---------------- fused: blocks 0..1023 decode codeword table; blocks 1024.. encode samples ----
#define DECB 1024
__global__ __launch_bounds__(256, 4) void vq_enc_dec(
    const float* __restrict__ x,
    const float* __restrict__ b1, const float* __restrict__ b2, const float* __restrict__ b3,
    const float* __restrict__ codebook, const float* __restrict__ decb,
    const float* __restrict__ d1b, const float* __restrict__ d2b, const float* __restrict__ d3b,
    const float* __restrict__ ws, ushort_t* __restrict__ hhi, ushort_t* __restrict__ hlo,
    float* __restrict__ table)
{
  __shared__ __align__(16) char SMEM[38688];
  const int t = threadIdx.x;
  const int lane = t & 63, wv = t >> 6;
  const int col = lane & 15, quad = lane >> 4;

  if (blockIdx.x >= DECB) {
    // ================= ENCODER PATH (round-8 code, verified) =================
    ushort_t* R0h = (ushort_t*)SMEM;            // 7840
    ushort_t* R0l = R0h + 7840;                 // 7840
    float*    XT  = (float*)(SMEM + 31360);     // 624
    ushort_t* C3h = R0h;                        // overlay
    ushort_t* C3l = R0l;
    const int b = blockIdx.x - DECB;

    for (int i = t; i < 3920; i += 256) { ((uint_t*)R0h)[i] = 0u; ((uint_t*)R0l)[i] = 0u; }
    const float* xb = x + (size_t)b * 576;
    for (int i = t; i < 624; i += 256) {
      int row = i / 26, c = i - row * 26;
      XT[i] = (c >= 1 && c <= 24) ? xb[row*24 + c - 1] : 0.f;
    }
    __syncthreads();

    // ---- conv1 ----
    {
      int co = t & 31, g = t >> 5, gy = g >> 1, gx = g & 1;
      float w[9];
      #pragma unroll
      for (int k = 0; k < 9; ++k) w[k] = ws[OFF_W1R + k*32 + co];
      float bias = b1[co];
      #pragma unroll
      for (int pr = 0; pr < 3; ++pr) {
        int Y = gy*6 + pr*2;
        float a0[12], a1[12];
        #pragma unroll
        for (int i = 0; i < 12; ++i) { a0[i] = 0.f; a1[i] = 0.f; }
        #pragma unroll
        for (int wy = 0; wy < 4; ++wy) {
          int ry = Y - 1 + wy;
          if (ry < 0 || ry > 23) continue;
          const float2* rp = (const float2*)&XT[ry*26 + gx*12];
          float r[14];
          #pragma unroll
          for (int k = 0; k < 7; ++k) { float2 p = rp[k]; r[2*k] = p.x; r[2*k+1] = p.y; }
          if (wy < 3) {
            #pragma unroll
            for (int xx = 0; xx < 12; ++xx)
              #pragma unroll
              for (int dx = 0; dx < 3; ++dx) a0[xx] += r[xx+dx] * w[wy*3+dx];
          }
          if (wy >= 1) {
            #pragma unroll
            for (int xx = 0; xx < 12; ++xx)
              #pragma unroll
              for (int dx = 0; dx < 3; ++dx) a1[xx] += r[xx+dx] * w[(wy-1)*3+dx];
          }
        }
        #pragma unroll
        for (int pc = 0; pc < 6; ++pc) {
          float m = fmaxf(fmaxf(a0[2*pc], a0[2*pc+1]), fmaxf(a1[2*pc], a1[2*pc+1]));
          float v = m + bias; v = v > 0.f ? v : 0.f;
          int row = gy*3 + pr, colp = gx*6 + pc;
          int addr = ((row+1)*14 + (colp+1))*40 + co;
          ushort_t hb = f2bf(v);
          R0h[addr] = hb;
          R0l[addr] = f2bf(v - bf2f(hb));
        }
      }
    }
    __syncthreads();

    // ---- conv2 MFMA ----
    {
      const int h = wv & 1, p = wv >> 1;
      const ushort_t* W2 = (const ushort_t*)(ws + OFF_W2BF);
      int baseA[5];
      #pragma unroll
      for (int mi = 0; mi < 5; ++mi) {
        int m = (h*5 + mi)*16 + col; if (m > 143) m = 143;
        int cell = m >> 2, sub = m & 3;
        int opy = cell / 6, opx = cell - opy*6;
        int y = 2*opy + (sub >> 1), xx = 2*opx + (sub & 1);
        baseA[mi] = (y*14 + xx)*40 + quad*8;
      }
      f32x4 acc[5][2];
      #pragma unroll
      for (int mi = 0; mi < 5; ++mi) { acc[mi][0] = (f32x4)0.f; acc[mi][1] = (f32x4)0.f; }
      const int co0 = p*32 + col, co1 = co0 + 16;
      #pragma unroll
      for (int t9 = 0; t9 < 9; ++t9) {
        const int TAPOFF = ((t9/3)*14 + (t9%3))*40;
        int bidx = t9*2048 + quad*8;
        short8 Bh0 = *(const short8*)(W2 + bidx + co0*32);
        short8 Bh1 = *(const short8*)(W2 + bidx + co1*32);
        short8 Bl0 = *(const short8*)(W2 + 18432 + bidx + co0*32);
        short8 Bl1 = *(const short8*)(W2 + 18432 + bidx + co1*32);
        #pragma unroll
        for (int mi = 0; mi < 5; ++mi) {
          int a = baseA[mi] + TAPOFF;
          short8 Ah = *(const short8*)(R0h + a);
          short8 Al = *(const short8*)(R0l + a);
          acc[mi][0] = __builtin_amdgcn_mfma_f32_16x16x32_bf16(Al, Bh0, acc[mi][0], 0, 0, 0);
          acc[mi][0] = __builtin_amdgcn_mfma_f32_16x16x32_bf16(Ah, Bl0, acc[mi][0], 0, 0, 0);
          acc[mi][0] = __builtin_amdgcn_mfma_f32_16x16x32_bf16(Ah, Bh0, acc[mi][0], 0, 0, 0);
          acc[mi][1] = __builtin_amdgcn_mfma_f32_16x16x32_bf16(Al, Bh1, acc[mi][1], 0, 0, 0);
          acc[mi][1] = __builtin_amdgcn_mfma_f32_16x16x32_bf16(Ah, Bl1, acc[mi][1], 0, 0, 0);
          acc[mi][1] = __builtin_amdgcn_mfma_f32_16x16x32_bf16(Ah, Bh1, acc[mi][1], 0, 0, 0);
        }
      }
      __syncthreads();
      for (int i = t; i < 2304; i += 256) { ((uint_t*)C3h)[i] = 0u; ((uint_t*)C3l)[i] = 0u; }
      __syncthreads();
      #pragma unroll
      for (int mi = 0; mi < 5; ++mi) {
        int cell = (h*5 + mi)*4 + quad;
        if (cell < 36) {
          int opy = cell / 6, opx = cell - opy*6;
          int wa = ((opy+1)*8 + (opx+1))*72;
          #pragma unroll
          for (int j = 0; j < 2; ++j) {
            int ch = j ? co1 : co0;
            f32x4 a = acc[mi][j];
            float v = fmaxf(fmaxf(a.x, a.y), fmaxf(a.z, a.w)) + b2[ch];
            v = v > 0.f ? v : 0.f;
            ushort_t hb = f2bf(v);
            C3h[wa + ch] = hb;
            C3l[wa + ch] = f2bf(v - bf2f(hb));
          }
        }
      }
    }
    __syncthreads();

    // ---- conv3 MFMA ----
    {
      const ushort_t* W3 = (const ushort_t*)(ws + OFF_W3BF);
      int baseA[3];
      #pragma unroll
      for (int mt = 0; mt < 3; ++mt) {
        int m = mt*16 + col; if (m > 35) m = 35;
        int cell = m >> 2, sub = m & 3;
        int opy = cell / 3, opx = cell - opy*3;
        int y = 2*opy + (sub >> 1), xx = 2*opx + (sub & 1);
        baseA[mt] = (y*8 + xx)*72 + quad*8;
      }
      f32x4 acc[3][2];
      #pragma unroll
      for (int mt = 0; mt < 3; ++mt) { acc[mt][0] = (f32x4)0.f; acc[mt][1] = (f32x4)0.f; }
      const int co0 = wv*16 + col, co1 = co0 + 64;
      #pragma unroll
      for (int ks = 0; ks < 18; ++ks) {
        const int t9 = ks >> 1, ch0 = (ks & 1)*32;
        const int TAPOFF = ((t9/3)*8 + (t9%3))*72;
        int bidx = t9*8192 + ch0 + quad*8;
        short8 Bh0 = *(const short8*)(W3 + bidx + co0*64);
        short8 Bh1 = *(const short8*)(W3 + bidx + co1*64);
        short8 Bl0 = *(const short8*)(W3 + 73728 + bidx + co0*64);
        short8 Bl1 = *(const short8*)(W3 + 73728 + bidx + co1*64);
        #pragma unroll
        for (int mt = 0; mt < 3; ++mt) {
          int a = baseA[mt] + TAPOFF + ch0;
          short8 Ah = *(const short8*)(C3h + a);
          short8 Al = *(const short8*)(C3l + a);
          acc[mt][0] = __builtin_amdgcn_mfma_f32_16x16x32_bf16(Al, Bh0, acc[mt][0], 0, 0, 0);
          acc[mt][0] = __builtin_amdgcn_mfma_f32_16x16x32_bf16(Ah, Bl0, acc[mt][0], 0, 0, 0);
          acc[mt][0] = __builtin_amdgcn_mfma_f32_16x16x32_bf16(Ah, Bh0, acc[mt][0], 0, 0, 0);
          acc[mt][1] = __builtin_amdgcn_mfma_f32_16x16x32_bf16(Al, Bh1, acc[mt][1], 0, 0, 0);
          acc[mt][1] = __builtin_amdgcn_mfma_f32_16x16x32_bf16(Ah, Bl1, acc[mt][1], 0, 0, 0);
          acc[mt][1] = __builtin_amdgcn_mfma_f32_16x16x32_bf16(Ah, Bh1, acc[mt][1], 0, 0, 0);
        }
      }
      ushort_t* hb_ = hhi + (size_t)b * 1152;
      ushort_t* lb_ = hlo + (size_t)b * 1152;
      #pragma unroll
      for (int mt = 0; mt < 3; ++mt) {
        int cell = mt*4 + quad;
        if (cell < 9) {
          #pragma unroll
          for (int j = 0; j < 2; ++j) {
            int ch = j ? co1 : co0;
            f32x4 a = acc[mt][j];
            float v = fmaxf(fmaxf(a.x, a.y), fmaxf(a.z, a.w)) + b3[ch];
            v = v > 0.f ? v : 0.f;
            ushort_t hb2 = f2bf(v);
            hb_[ch*9 + cell] = hb2;
            lb_[ch*9 + cell] = f2bf(v - bf2f(hb2));
          }
        }
      }
    }
    return;
  }

  // ================= DECODE-TABLE PATH (round-8 code, verified) =================
  {
    float* POOL = (float*)SMEM;                 // 8008
    float* PS   = (float*)(SMEM + 32032);       // 1536
    float* ZQ   = (float*)(SMEM + 38176);       // 128
    ushort_t* FAh = (ushort_t*)POOL;
    ushort_t* FAl = FAh + 3400;
    ushort_t* GAh = (ushort_t*)(POOL + 3400);
    ushort_t* GAl = GAh + 4608;
    float* R2 = POOL;
    const int cw = blockIdx.x;

    for (int i = t; i < 8008; i += 256) POOL[i] = 0.f;
    if (t < 128) ZQ[t] = codebook[(size_t)cw*128 + t];
    __syncthreads();

    #pragma unroll
    for (int p = 0; p < 5; ++p) {
      int j = t + p*256;
      if (j < 1152) {
        float a0 = decb[j];
        const float* wb = ws + OFF_DWT + j;
        #pragma unroll 4
        for (int k = 0; k < 128; ++k) a0 += wb[k*1152] * ZQ[k];
        int ci = j / 9, rem = j - ci*9;
        int pix = ((rem/3)+1)*5 + (rem%3) + 1;
        ushort_t hb = f2bf(a0);
        FAh[pix*136 + ci] = hb;
        FAl[pix*136 + ci] = f2bf(a0 - bf2f(hb));
      }
    }
    __syncthreads();

    const ushort_t* BD1 = (const ushort_t*)(ws + OFF_BD1F);
    f32x4 acc1 = (f32x4)0.f;
    {
      const int m9 = col < 9 ? col : 8;
      const int oy = m9/3, ox = m9 - oy*3;
      const int co = wv*16 + col;
      #pragma unroll 4
      for (int ks = 0; ks < 36; ++ks) {
        int kb = ks*32 + quad*8;
        int tap = kb >> 7, ci0 = kb & 127;
        int pix = (oy + tap/3)*5 + ox + tap%3;
        short8 Ah = *(const short8*)(FAh + pix*136 + ci0);
        short8 Al = *(const short8*)(FAl + pix*136 + ci0);
        const ushort_t* bp = BD1 + co*1152 + kb;
        short8 Bh = *(const short8*)bp;
        short8 Bl = *(const short8*)(bp + 73728);
        acc1 = __builtin_amdgcn_mfma_f32_16x16x32_bf16(Al, Bh, acc1, 0, 0, 0);
        acc1 = __builtin_amdgcn_mfma_f32_16x16x32_bf16(Ah, Bl, acc1, 0, 0, 0);
        acc1 = __builtin_amdgcn_mfma_f32_16x16x32_bf16(Ah, Bh, acc1, 0, 0, 0);
      }
    }
    {
      const int co = wv*16 + col;
      float bias = d1b[co];
      #pragma unroll
      for (int r = 0; r < 4; ++r) {
        int m = quad*4 + r;
        if (m < 9) {
          int oy = m/3, ox = m - oy*3;
          float v = acc1[r] + bias; v = v > 0.f ? v : 0.f;
          ushort_t hb = f2bf(v), lb = f2bf(v - bf2f(hb));
          int rbase = (2*oy+1)*8 + (2*ox+1);
          GAh[(rbase  )*72 + co] = hb; GAh[(rbase+1)*72 + co] = hb;
          GAh[(rbase+8)*72 + co] = hb; GAh[(rbase+9)*72 + co] = hb;
          GAl[(rbase  )*72 + co] = lb; GAl[(rbase+1)*72 + co] = lb;
          GAl[(rbase+8)*72 + co] = lb; GAl[(rbase+9)*72 + co] = lb;
        }
      }
    }
    __syncthreads();

    const ushort_t* BD2 = (const ushort_t*)(ws + OFF_BD2F);
    f32x4 acc2[3];
    acc2[0] = (f32x4)0.f; acc2[1] = (f32x4)0.f; acc2[2] = (f32x4)0.f;
    const int h = wv >> 1, js = (wv & 1)*3;
    for (int ks = h*9; ks < h*9 + 9; ++ks) {
      int kb = ks*32 + quad*8;
      int tap = kb >> 6, ci0 = kb & 63;
      int ty = tap/3, tx = tap - ty*3;
      #pragma unroll
      for (int jj = 0; jj < 3; ++jj) {
        int job = js + jj;
        int mt = job >> 1, nt = job & 1;
        int m = mt*16 + col; if (m > 35) m = 35;
        int oy = m/6, ox = m - oy*6;
        int pix = (oy+ty)*8 + ox+tx;
        short8 Ah = *(const short8*)(GAh + pix*72 + ci0);
        short8 Al = *(const short8*)(GAl + pix*72 + ci0);
        int co = nt*16 + col;
        const ushort_t* bp = BD2 + co*576 + kb;
        short8 Bh = *(const short8*)bp;
        short8 Bl = *(const short8*)(bp + 18432);
        acc2[jj] = __builtin_amdgcn_mfma_f32_16x16x32_bf16(Al, Bh, acc2[jj], 0, 0, 0);
        acc2[jj] = __builtin_amdgcn_mfma_f32_16x16x32_bf16(Ah, Bl, acc2[jj], 0, 0, 0);
        acc2[jj] = __builtin_amdgcn_mfma_f32_16x16x32_bf16(Ah, Bh, acc2[jj], 0, 0, 0);
      }
    }
    __syncthreads();
    if (h == 1) {
      #pragma unroll
      for (int jj = 0; jj < 3; ++jj) {
        int job = js + jj;
        #pragma unroll
        for (int r = 0; r < 4; ++r) PS[(job*64 + lane)*4 + r] = acc2[jj][r];
      }
    }
    for (int i = t; i < 6468; i += 256) R2[i] = 0.f;
    __syncthreads();
    if (h == 0) {
      #pragma unroll
      for (int jj = 0; jj < 3; ++jj) {
        int job = js + jj;
        int mt = job >> 1, nt = job & 1;
        int co = nt*16 + col;
        float bias = d2b[co];
        #pragma unroll
        for (int r = 0; r < 4; ++r) {
          float v = acc2[jj][r] + PS[(job*64 + lane)*4 + r];
          int m = mt*16 + quad*4 + r;
          if (m < 36) {
            int oy = m/6, ox = m - oy*6;
            v += bias; v = v > 0.f ? v : 0.f;
            int rbase = (2*oy+1)*14 + (2*ox+1);
            R2[(rbase   )*33 + co] = v; R2[(rbase+ 1)*33 + co] = v;
            R2[(rbase+14)*33 + co] = v; R2[(rbase+15)*33 + co] = v;
          }
        }
      }
    }
    __syncthreads();

    if (t < 144) {
      int yy = t / 12, xx = t - yy*12;
      const float* w3 = ws + OFF_D3R;
      float acc = d3b[0];
      #pragma unroll
      for (int dy = 0; dy < 3; ++dy)
        #pragma unroll
        for (int dx = 0; dx < 3; ++dx) {
          const float* rp = &R2[((yy+dy)*14 + xx+dx)*33];
          const float* wp = w3 + dy*3 + dx;
          #pragma unroll 8
          for (int ci = 0; ci < 32; ++ci) acc += rp[ci] * wp[ci*9];
        }
      float v = acc > 0.f ? acc : 0.f;
      float* ob = table + (size_t)cw * 576;
      int o0 = (2*yy)*24 + 2*xx;
      ob[o0] = v; ob[o0+1] = v; ob[o0+24] = v; ob[o0+25] = v;
    }
  }
}

// ---------------- fused enc_fc + argmin + scatter: 32 samples/block, 256 blocks -------------
__global__ __launch_bounds__(256, 2) void vq_fc_argmin_scatter(
    const float* __restrict__ efb, const float* __restrict__ ws,
    const ushort_t* __restrict__ hhi, const ushort_t* __restrict__ hlo,
    const float* __restrict__ table, float* __restrict__ out)
{
  __shared__ float ZL[32*132];
  __shared__ float WVs[128];
  __shared__ int   WIs[128];
  __shared__ int   IDX[32];
  const int t = threadIdx.x;
  const int sb = blockIdx.x * 32;
  const int lane = t & 63, wv = t >> 6;
  const int col = lane & 15, quad = lane >> 4;

  const ushort_t* EW  = (const ushort_t*)(ws + OFF_EWT);
  const ushort_t* CBB = (const ushort_t*)(ws + OFF_CT);

  // ---- enc_fc: z = h @ efw^T + b (M=32: 2 m-tiles; N=128: wave owns 2 n-tiles) ----
  f32x4 acc[2][2];
  acc[0][0] = (f32x4)0.f; acc[0][1] = (f32x4)0.f;
  acc[1][0] = (f32x4)0.f; acc[1][1] = (f32x4)0.f;
  const size_t hrow0 = (size_t)(sb + col) * 1152 + quad*8;
  const size_t hrow1 = (size_t)(sb + 16 + col) * 1152 + quad*8;
  const int n0 = wv*32 + col, n1 = n0 + 16;
  #pragma unroll 2
  for (int ks = 0; ks < 36; ++ks) {
    short8 Ah0 = *(const short8*)(hhi + hrow0 + ks*32);
    short8 Al0 = *(const short8*)(hlo + hrow0 + ks*32);
    short8 Ah1 = *(const short8*)(hhi + hrow1 + ks*32);
    short8 Al1 = *(const short8*)(hlo + hrow1 + ks*32);
    const ushort_t* bp0 = EW + (ks*128 + n0)*32 + quad*8;
    const ushort_t* bp1 = EW + (ks*128 + n1)*32 + quad*8;
    short8 Bh0 = *(const short8*)(bp0);
    short8 Bl0 = *(const short8*)(bp0 + 147456);
    short8 Bh1 = *(const short8*)(bp1);
    short8 Bl1 = *(const short8*)(bp1 + 147456);
    acc[0][0] = __builtin_amdgcn_mfma_f32_16x16x32_bf16(Al0, Bh0, acc[0][0], 0, 0, 0);
    acc[0][0] = __builtin_amdgcn_mfma_f32_16x16x32_bf16(Ah0, Bl0, acc[0][0], 0, 0, 0);
    acc[0][0] = __builtin_amdgcn_mfma_f32_16x16x32_bf16(Ah0, Bh0, acc[0][0], 0, 0, 0);
    acc[0][1] = __builtin_amdgcn_mfma_f32_16x16x32_bf16(Al0, Bh1, acc[0][1], 0, 0, 0);
    acc[0][1] = __builtin_amdgcn_mfma_f32_16x16x32_bf16(Ah0, Bl1, acc[0][1], 0, 0, 0);
    acc[0][1] = __builtin_amdgcn_mfma_f32_16x16x32_bf16(Ah0, Bh1, acc[0][1], 0, 0, 0);
    acc[1][0] = __builtin_amdgcn_mfma_f32_16x16x32_bf16(Al1, Bh0, acc[1][0], 0, 0, 0);
    acc[1][0] = __builtin_amdgcn_mfma_f32_16x16x32_bf16(Ah1, Bl0, acc[1][0], 0, 0, 0);
    acc[1][0] = __builtin_amdgcn_mfma_f32_16x16x32_bf16(Ah1, Bh0, acc[1][0], 0, 0, 0);
    acc[1][1] = __builtin_amdgcn_mfma_f32_16x16x32_bf16(Al1, Bh1, acc[1][1], 0, 0, 0);
    acc[1][1] = __builtin_amdgcn_mfma_f32_16x16x32_bf16(Ah1, Bl1, acc[1][1], 0, 0, 0);
    acc[1][1] = __builtin_amdgcn_mfma_f32_16x16x32_bf16(Ah1, Bh1, acc[1][1], 0, 0, 0);
  }
  {
    float bs0 = efb[n0], bs1 = efb[n1];
    #pragma unroll
    for (int m2 = 0; m2 < 2; ++m2) {
      #pragma unroll
      for (int r = 0; r < 4; ++r) {
        int m = m2*16 + quad*4 + r;
        ZL[m*132 + n0] = acc[m2][0][r] + bs0;
        ZL[m*132 + n1] = acc[m2][1][r] + bs1;
      }
    }
  }
  __syncthreads();

  // ---- z A-frags (hi/lo) for both m-tiles ----
  short8 zAh[2][4], zAl[2][4];
  #pragma unroll
  for (int m2 = 0; m2 < 2; ++m2) {
    #pragma unroll
    for (int ks = 0; ks < 4; ++ks) {
      const float* zp = &ZL[(m2*16 + col)*132 + ks*32 + quad*8];
      float4 z0 = *(const float4*)zp;
      float4 z1 = *(const float4*)(zp + 4);
      float zv[8] = {z0.x, z0.y, z0.z, z0.w, z1.x, z1.y, z1.z, z1.w};
      ushort_t ph[8], pl[8];
      #pragma unroll
      for (int e = 0; e < 8; ++e) {
        ushort_t hb = f2bf(zv[e]);
        ph[e] = hb; pl[e] = f2bf(zv[e] - bf2f(hb));
      }
      zAh[m2][ks] = *(const short8*)ph;
      zAl[m2][ks] = *(const short8*)pl;
    }
  }

  // ---- distances (M=32, K=128, N=1024; wave owns 16 n-tiles) ----
  float bestv[2][4]; int besti[2][4];
  #pragma unroll
  for (int m2 = 0; m2 < 2; ++m2)
    #pragma unroll
    for (int r = 0; r < 4; ++r) { bestv[m2][r] = 3.4e38f; besti[m2][r] = 0; }
  for (int c4 = 0; c4 < 4; ++c4) {
    f32x4 dacc[2][4];
    #pragma unroll
    for (int m2 = 0; m2 < 2; ++m2)
      #pragma unroll
      for (int nn = 0; nn < 4; ++nn) dacc[m2][nn] = (f32x4)0.f;
    #pragma unroll
    for (int ks = 0; ks < 4; ++ks) {
      #pragma unroll
      for (int nn = 0; nn < 4; ++nn) {
        int cw = (wv*16 + c4*4 + nn)*16 + col;
        const ushort_t* bp = CBB + (size_t)(ks*1024 + cw)*32 + quad*8;
        short8 Bh = *(const short8*)bp;
        short8 Bl = *(const short8*)(bp + 131072);
        #pragma unroll
        for (int m2 = 0; m2 < 2; ++m2) {
          dacc[m2][nn] = __builtin_amdgcn_mfma_f32_16x16x32_bf16(zAl[m2][ks], Bh, dacc[m2][nn], 0, 0, 0);
          dacc[m2][nn] = __builtin_amdgcn_mfma_f32_16x16x32_bf16(zAh[m2][ks], Bl, dacc[m2][nn], 0, 0, 0);
          dacc[m2][nn] = __builtin_amdgcn_mfma_f32_16x16x32_bf16(zAh[m2][ks], Bh, dacc[m2][nn], 0, 0, 0);
        }
      }
    }
    #pragma unroll
    for (int nn = 0; nn < 4; ++nn) {
      int cw = (wv*16 + c4*4 + nn)*16 + col;
      float ccv = ws[OFF_CC + cw];
      #pragma unroll
      for (int m2 = 0; m2 < 2; ++m2)
        #pragma unroll
        for (int r = 0; r < 4; ++r) {
          float dist = ccv - 2.f*dacc[m2][nn][r];
          if (dist < bestv[m2][r]) { bestv[m2][r] = dist; besti[m2][r] = cw; }
        }
    }
  }

  // ---- reduce over the 16 cols of each quad ----
  #pragma unroll
  for (int m2 = 0; m2 < 2; ++m2)
    #pragma unroll
    for (int r = 0; r < 4; ++r) {
      float v = bestv[m2][r]; int ii = besti[m2][r];
      #pragma unroll
      for (int off = 8; off >= 1; off >>= 1) {
        float v2 = __shfl_xor(v, off); int i2 = __shfl_xor(ii, off);
        if (v2 < v || (v2 == v && i2 < ii)) { v = v2; ii = i2; }
      }
      if (col == 0) {
        int m = m2*16 + quad*4 + r;
        WVs[wv*32 + m] = v; WIs[wv*32 + m] = ii;
      }
    }
  __syncthreads();
  if (t < 32) {
    float v = WVs[t]; int ii = WIs[t];
    #pragma unroll
    for (int w2 = 1; w2 < 4; ++w2) {
      float v2 = WVs[w2*32 + t]; int i2 = WIs[w2*32 + t];
      if (v2 < v || (v2 == v && i2 < ii)) { v = v2; ii = i2; }
    }
    IDX[t] = ii;
  }
  __syncthreads();

  // ---- scatter: out[s] = table[IDX[s]] (table L2-resident) ----
  const float4* tb4 = (const float4*)table;
  float4* out4 = (float4*)(out + (size_t)sb * 576);
  for (int i = t; i < 32*144; i += 256) {
    int s = i / 144, r = i - s*144;
    out4[s*144 + r] = tb4[(size_t)IDX[s]*144 + r];
  }
}

extern "C" void kernel_launch(void* const* d_in, const int* in_sizes, int n_in,
                              void* d_out, int out_size, void* d_ws, size_t ws_size,
                              hipStream_t stream) {
  const float* x   = (const float*)d_in[0];
  const float* c1w = (const float*)d_in[1];
  const float* c1b = (const float*)d_in[2];
  const float* c2w = (const float*)d_in[3];
  const float* c2b = (const float*)d_in[4];
  const float* c3w = (const float*)d_in[5];
  const float* c3b = (const float*)d_in[6];
  const float* efw = (const float*)d_in[7];
  const float* efb = (const float*)d_in[8];
  const float* cb  = (const float*)d_in[9];
  const float* dfw = (const float*)d_in[10];
  const float* dfb = (const float*)d_in[11];
  const float* dw1 = (const float*)d_in[12];
  const float* db1 = (const float*)d_in[13];
  const float* dw2 = (const float*)d_in[14];
  const float* db2 = (const float*)d_in[15];
  const float* dw3 = (const float*)d_in[16];
  const float* db3 = (const float*)d_in[17];
  float* ws = (float*)d_ws;
  ushort_t* hhi  = (ushort_t*)(ws + OFF_H);
  ushort_t* hlo  = hhi + (size_t)8192*1152;
  float* table = ws + OFF_TABLE;
  float* outp = (float*)d_out;
  int B = in_sizes[0] / 576;

  vq_prep_all<<<(PREP_N + 255) / 256, 256, 0, stream>>>(c1w, c2w, c3w, efw, cb, dfw, dw1, dw2, dw3, ws);
  vq_enc_dec<<<DECB + B, 256, 0, stream>>>(x, c1b, c2b, c3b, cb, dfb, db1, db2, db3,
                                           ws, hhi, hlo, table);
  vq_fc_argmin_scatter<<<B/32, 256, 0, stream>>>(efb, ws, hhi, hlo, table, outp);
}